// Round 1
// baseline (2004.718 us; speedup 1.0000x reference)
//
#include <hip/hip_runtime.h>
#include <math.h>

#define BB 4
#define CI 6
#define LL 4096
#define DMC 72
#define DIC 144
#define KD 4
#define NS 8
#define RD 4
#define NLAYER 2
#define GRP 12
#define NCH 128   // chunks per scan
#define TS 32     // steps per chunk

__device__ __forceinline__ float sigmoidf_(float x){ return 1.f/(1.f+__expf(-x)); }
__device__ __forceinline__ float siluf_(float x){ return x*sigmoidf_(x); }
__device__ __forceinline__ float softplusf_(float x){ return fmaxf(x,0.f) + log1pf(__expf(-fabsf(x))); }

// spatial position p (row-major h*64+w) for scan index l of direction k
__device__ __forceinline__ int dirmap(int k, int l){
  switch(k & 3){
    case 0: return l;
    case 1: return ((l & 63) << 6) | (l >> 6);
    case 2: return (LL-1) - l;
    default: { int m = (LL-1) - l; return ((m & 63) << 6) | (m >> 6); }
  }
}

// ---------- conv 6->72 3x3 + lrelu(0.01) ----------
__global__ void k_conv1(const float* __restrict__ img, const float* __restrict__ w,
                        const float* __restrict__ bias, float* __restrict__ out){
  int idx = blockIdx.x*256 + threadIdx.x;
  if (idx >= BB*DMC*LL) return;
  int p = idx & 4095; int o = (idx>>12) % DMC; int b = idx / (DMC*LL);
  int h = p>>6, wx = p&63;
  float acc = bias[o];
  for (int ic=0; ic<CI; ++ic){
    const float* ip = img + ((b*CI+ic)<<12);
    const float* wp = w + (o*CI+ic)*9;
    #pragma unroll
    for (int kh=0; kh<3; ++kh){
      int hy = h+kh-1; if ((unsigned)hy >= 64u) continue;
      #pragma unroll
      for (int kw=0; kw<3; ++kw){
        int wxx = wx+kw-1; if ((unsigned)wxx >= 64u) continue;
        acc += ip[(hy<<6)+wxx]*wp[kh*3+kw];
      }
    }
  }
  out[idx] = acc >= 0.f ? acc : 0.01f*acc;
}

// ---------- conv 72->72 3x3 + 1x1 shortcut + lrelu(0.01), 4 oc/thread ----------
__global__ void k_conv2(const float* __restrict__ hin, const float* __restrict__ img,
                        const float* __restrict__ w2, const float* __restrict__ b2,
                        const float* __restrict__ wsc, const float* __restrict__ bsc,
                        float* __restrict__ xout){
  int idx = blockIdx.x*256 + threadIdx.x;
  if (idx >= BB*18*LL) return;
  int p = idx & 4095; int og = (idx>>12) % 18; int b = idx / (18*LL);
  int h = p>>6, wx = p&63;
  float acc[4];
  #pragma unroll
  for (int j=0;j<4;++j) acc[j] = b2[og*4+j] + bsc[og*4+j];
  for (int ic=0; ic<DMC; ++ic){
    const float* ip = hin + ((b*DMC+ic)<<12);
    const float* wp = w2 + (og*4)*DMC*9 + ic*9;
    #pragma unroll
    for (int kh=0; kh<3; ++kh){
      int hy = h+kh-1; if ((unsigned)hy >= 64u) continue;
      #pragma unroll
      for (int kw=0; kw<3; ++kw){
        int wxx = wx+kw-1; if ((unsigned)wxx >= 64u) continue;
        float v = ip[(hy<<6)+wxx];
        #pragma unroll
        for (int j=0;j<4;++j) acc[j] += v * wp[j*DMC*9 + kh*3+kw];
      }
    }
  }
  for (int ic=0; ic<CI; ++ic){
    float v = img[((b*CI+ic)<<12)+p];
    #pragma unroll
    for (int j=0;j<4;++j) acc[j] += v * wsc[(og*4+j)*CI+ic];
  }
  #pragma unroll
  for (int j=0;j<4;++j){
    float a = acc[j];
    xout[((b*DMC+og*4+j)<<12)+p] = a >= 0.f ? a : 0.01f*a;
  }
}

// ---------- xz = in_w(288x72) . x, 4 out-ch/thread ----------
__global__ void k_xz(const float* __restrict__ x, const float* __restrict__ inw,
                     float* __restrict__ xz){
  int idx = blockIdx.x*256 + threadIdx.x;
  if (idx >= BB*DMC*LL) return;  // 72 groups of 4 = 288 outputs
  int p = idx & 4095; int eg = (idx>>12) % DMC; int b = idx / (DMC*LL);
  float acc[4] = {0.f,0.f,0.f,0.f};
  for (int c=0; c<DMC; ++c){
    float v = x[((b*DMC+c)<<12)+p];
    #pragma unroll
    for (int j=0;j<4;++j) acc[j] += v * inw[(eg*4+j)*DMC + c];
  }
  #pragma unroll
  for (int j=0;j<4;++j) xz[((b*2*DIC+eg*4+j)<<12)+p] = acc[j];
}

// ---------- depthwise 3x3 + bias + silu on xz[:, :144] -> xi ----------
__global__ void k_dw(const float* __restrict__ xz, const float* __restrict__ dww,
                     const float* __restrict__ dwb, float* __restrict__ xi){
  int idx = blockIdx.x*256 + threadIdx.x;
  if (idx >= BB*DIC*LL) return;
  int p = idx & 4095; int c = (idx>>12) % DIC; int b = idx / (DIC*LL);
  int h = p>>6, wx = p&63;
  const float* ip = xz + ((b*2*DIC+c)<<12);
  const float* wp = dww + c*9;
  float acc = dwb[c];
  #pragma unroll
  for (int kh=0; kh<3; ++kh){
    int hy = h+kh-1; if ((unsigned)hy >= 64u) continue;
    #pragma unroll
    for (int kw=0; kw<3; ++kw){
      int wxx = wx+kw-1; if ((unsigned)wxx >= 64u) continue;
      acc += ip[(hy<<6)+wxx]*wp[kh*3+kw];
    }
  }
  xi[idx] = siluf_(acc);
}

// ---------- x_dbl[b,k,c20,l] = sum_d xs[b,k,d,l]*xp_w[k,c20,d], thread per (b,k,l) ----------
__global__ void k_xdbl(const float* __restrict__ xi, const float* __restrict__ xpw,
                       float* __restrict__ xdbl){
  int idx = blockIdx.x*256 + threadIdx.x;
  if (idx >= BB*KD*LL) return;
  int l = idx & 4095; int k = (idx>>12) & 3; int b = idx >> 14;
  int p = dirmap(k,l);
  const float* xib = xi + (size_t)b*DIC*LL + p;
  const float* wp = xpw + k*20*DIC;
  float acc[20];
  #pragma unroll
  for (int c=0;c<20;++c) acc[c]=0.f;
  for (int d=0; d<DIC; ++d){
    float v = xib[d<<12];
    #pragma unroll
    for (int c=0;c<20;++c) acc[c] += v * wp[c*DIC+d];
  }
  #pragma unroll
  for (int c=0;c<20;++c) xdbl[((size_t)(b*KD+k)*20+c)*LL + l] = acc[c];
}

__device__ __forceinline__ void scan_decode(int idx, int& b, int& k, int& ch, int& c){
  c = idx % DIC;
  int r = idx / DIC;
  ch = r % NCH;
  r /= NCH;
  k = r & 3; b = r >> 2;
}

// ---------- P1: per-chunk summaries (cumA, partial state) ----------
__global__ void k_p1(const float* __restrict__ xi, const float* __restrict__ xdbl,
                     const float* __restrict__ dtpw, const float* __restrict__ dtpb,
                     const float* __restrict__ alog,
                     float* __restrict__ cumA, float* __restrict__ hp){
  int idx = blockIdx.x*256 + threadIdx.x;
  if (idx >= BB*KD*NCH*DIC) return;
  int b,k,ch,c; scan_decode(idx,b,k,ch,c);
  float Arow[NS];
  #pragma unroll
  for (int n=0;n<NS;++n) Arow[n] = -__expf(alog[(k*DIC+c)*NS+n]);
  float wdt[RD];
  #pragma unroll
  for (int r=0;r<RD;++r) wdt[r] = dtpw[(k*DIC+c)*RD+r];
  float bdt = dtpb[k*DIC+c];
  const float* xd = xdbl + (size_t)(b*KD+k)*20*LL;
  const float* xib = xi + (size_t)b*DIC*LL + (size_t)c*LL;
  float h[NS];
  #pragma unroll
  for (int n=0;n<NS;++n) h[n]=0.f;
  float sumd = 0.f;
  for (int t=0; t<TS; ++t){
    int l = ch*TS + t;
    float dt = bdt;
    #pragma unroll
    for (int r=0;r<RD;++r) dt += xd[r*LL + l]*wdt[r];
    dt = softplusf_(dt);
    sumd += dt;
    float u = xib[dirmap(k,l)];
    float du = dt*u;
    #pragma unroll
    for (int n=0;n<NS;++n){
      float Bn = xd[(RD+n)*LL + l];
      h[n] = h[n]*__expf(dt*Arow[n]) + du*Bn;
    }
  }
  size_t base = (size_t)idx*NS;
  #pragma unroll
  for (int n=0;n<NS;++n) hp[base+n] = h[n];
  #pragma unroll
  for (int n=0;n<NS;++n) cumA[base+n] = __expf(sumd*Arow[n]);
}

// ---------- P2: prefix over chunk summaries; hp becomes h_in ----------
__global__ void k_p2(const float* __restrict__ cumA, float* __restrict__ hp){
  int idx = blockIdx.x*256 + threadIdx.x;
  if (idx >= BB*KD*DIC) return;
  int c = idx % DIC; int bk = idx / DIC;
  float h[NS];
  #pragma unroll
  for (int n=0;n<NS;++n) h[n]=0.f;
  for (int ch=0; ch<NCH; ++ch){
    size_t base = ((size_t)(bk*NCH + ch)*DIC + c)*NS;
    #pragma unroll
    for (int n=0;n<NS;++n){
      float a = cumA[base+n];
      float pp = hp[base+n];
      float hv = h[n];
      hp[base+n] = hv;          // store h_in for this chunk
      h[n] = a*hv + pp;
    }
  }
}

// ---------- P3: replay chunks, accumulate y (4 directions) atomically ----------
__global__ void k_p3(const float* __restrict__ xi, const float* __restrict__ xdbl,
                     const float* __restrict__ dtpw, const float* __restrict__ dtpb,
                     const float* __restrict__ alog, const float* __restrict__ Dsv,
                     const float* __restrict__ hin, float* __restrict__ ybuf){
  int idx = blockIdx.x*256 + threadIdx.x;
  if (idx >= BB*KD*NCH*DIC) return;
  int b,k,ch,c; scan_decode(idx,b,k,ch,c);
  float Arow[NS];
  #pragma unroll
  for (int n=0;n<NS;++n) Arow[n] = -__expf(alog[(k*DIC+c)*NS+n]);
  float wdt[RD];
  #pragma unroll
  for (int r=0;r<RD;++r) wdt[r] = dtpw[(k*DIC+c)*RD+r];
  float bdt = dtpb[k*DIC+c];
  float Dv = Dsv[k*DIC+c];
  const float* xd = xdbl + (size_t)(b*KD+k)*20*LL;
  const float* xib = xi + (size_t)b*DIC*LL + (size_t)c*LL;
  float* yb = ybuf + (size_t)(b*DIC+c)*LL;
  float h[NS];
  size_t base = (size_t)idx*NS;
  #pragma unroll
  for (int n=0;n<NS;++n) h[n] = hin[base+n];
  for (int t=0; t<TS; ++t){
    int l = ch*TS + t;
    float dt = bdt;
    #pragma unroll
    for (int r=0;r<RD;++r) dt += xd[r*LL + l]*wdt[r];
    dt = softplusf_(dt);
    int p = dirmap(k,l);
    float u = xib[p];
    float du = dt*u;
    float y = 0.f;
    #pragma unroll
    for (int n=0;n<NS;++n){
      h[n] = h[n]*__expf(dt*Arow[n]) + du*xd[(RD+n)*LL + l];
      y += h[n]*xd[(RD+NS+n)*LL + l];
    }
    y += u*Dv;
    atomicAdd(yb + p, y);
  }
}

// ---------- LN over di per (b,p), *ong+onb, * silu(z) ; in place on ybuf ----------
__global__ void k_lnz(float* __restrict__ ybuf, const float* __restrict__ xz,
                      const float* __restrict__ ong, const float* __restrict__ onb){
  int idx = blockIdx.x*256 + threadIdx.x;
  if (idx >= BB*LL) return;
  int b = idx >> 12; int p = idx & 4095;
  float s=0.f, s2=0.f;
  for (int c=0;c<DIC;++c){
    float v = ybuf[((size_t)(b*DIC+c)<<12)+p];
    s += v; s2 += v*v;
  }
  float mu = s*(1.f/DIC);
  float var = s2*(1.f/DIC) - mu*mu;
  float rs = rsqrtf(var + 1e-5f);
  for (int c=0;c<DIC;++c){
    size_t off = ((size_t)(b*DIC+c)<<12)+p;
    float v = (ybuf[off]-mu)*rs*ong[c] + onb[c];
    float zv = xz[((size_t)(b*2*DIC+DIC+c)<<12)+p];
    ybuf[off] = v * siluf_(zv);
  }
}

// ---------- out-proj 72 = op_w(72x144) . y, 4 oc/thread ----------
__global__ void k_oproj(const float* __restrict__ ybuf, const float* __restrict__ opw,
                        float* __restrict__ xout){
  int idx = blockIdx.x*256 + threadIdx.x;
  if (idx >= BB*18*LL) return;
  int p = idx & 4095; int og = (idx>>12) % 18; int b = idx / (18*LL);
  float acc[4] = {0.f,0.f,0.f,0.f};
  for (int d=0; d<DIC; ++d){
    float v = ybuf[((size_t)(b*DIC+d)<<12)+p];
    #pragma unroll
    for (int j=0;j<4;++j) acc[j] += v * opw[(og*4+j)*DIC + d];
  }
  #pragma unroll
  for (int j=0;j<4;++j) xout[((size_t)(b*DMC+og*4+j)<<12)+p] = acc[j];
}

// ---------- groupnorm (12 groups of 6ch) in place ----------
__global__ void k_gn(float* __restrict__ x, const float* __restrict__ g,
                     const float* __restrict__ bta){
  __shared__ float s1[256], s2[256];
  int b = blockIdx.x / GRP; int gr = blockIdx.x % GRP;
  const int CG = DMC/GRP; // 6
  float ls=0.f, lq=0.f;
  for (int i = threadIdx.x; i < CG*LL; i += 256){
    int c = gr*CG + (i>>12); int p = i & 4095;
    float v = x[((size_t)(b*DMC+c)<<12)+p];
    ls += v; lq += v*v;
  }
  s1[threadIdx.x]=ls; s2[threadIdx.x]=lq; __syncthreads();
  for (int s=128; s>0; s>>=1){
    if (threadIdx.x < s){ s1[threadIdx.x]+=s1[threadIdx.x+s]; s2[threadIdx.x]+=s2[threadIdx.x+s]; }
    __syncthreads();
  }
  float mu = s1[0]/(CG*LL);
  float var = s2[0]/(CG*LL) - mu*mu;
  float rs = rsqrtf(var + 1e-5f);
  for (int i = threadIdx.x; i < CG*LL; i += 256){
    int c = gr*CG + (i>>12); int p = i & 4095;
    size_t off = ((size_t)(b*DMC+c)<<12)+p;
    x[off] = (x[off]-mu)*rs*g[c] + bta[c];
  }
}

// ---------- dense 72x72 + bias (+ optional lrelu 0.04), 4 oc/thread ----------
__global__ void k_dense(const float* __restrict__ xin, const float* __restrict__ w,
                        const float* __restrict__ bias, float* __restrict__ xout,
                        int do_lrelu){
  int idx = blockIdx.x*256 + threadIdx.x;
  if (idx >= BB*18*LL) return;
  int p = idx & 4095; int og = (idx>>12) % 18; int b = idx / (18*LL);
  float acc[4];
  #pragma unroll
  for (int j=0;j<4;++j) acc[j] = bias[og*4+j];
  for (int c=0; c<DMC; ++c){
    float v = xin[((size_t)(b*DMC+c)<<12)+p];
    #pragma unroll
    for (int j=0;j<4;++j) acc[j] += v * w[(og*4+j)*DMC + c];
  }
  #pragma unroll
  for (int j=0;j<4;++j){
    float a = acc[j];
    if (do_lrelu) a = a >= 0.f ? a : 0.04f*a;
    xout[((size_t)(b*DMC+og*4+j)<<12)+p] = a;
  }
}

// ---------- shrink conv 72->6 3x3 + sigmoid ----------
__global__ void k_shrink(const float* __restrict__ x, const float* __restrict__ w,
                         const float* __restrict__ bias, float* __restrict__ out){
  int idx = blockIdx.x*256 + threadIdx.x;
  if (idx >= BB*CI*LL) return;
  int p = idx & 4095; int o = (idx>>12) % CI; int b = idx / (CI*LL);
  int h = p>>6, wx = p&63;
  float acc = bias[o];
  for (int ic=0; ic<DMC; ++ic){
    const float* ip = x + ((size_t)(b*DMC+ic)<<12);
    const float* wp = w + (o*DMC+ic)*9;
    #pragma unroll
    for (int kh=0; kh<3; ++kh){
      int hy = h+kh-1; if ((unsigned)hy >= 64u) continue;
      #pragma unroll
      for (int kw=0; kw<3; ++kw){
        int wxx = wx+kw-1; if ((unsigned)wxx >= 64u) continue;
        acc += ip[(hy<<6)+wxx]*wp[kh*3+kw];
      }
    }
  }
  out[idx] = sigmoidf_(acc);
}

extern "C" void kernel_launch(void* const* d_in, const int* in_sizes, int n_in,
                              void* d_out, int out_size, void* d_ws, size_t ws_size,
                              hipStream_t stream){
  const float* image = (const float*)d_in[0];
  const float* cb_w1 = (const float*)d_in[1];
  const float* cb_b1 = (const float*)d_in[2];
  const float* cb_w2 = (const float*)d_in[3];
  const float* cb_b2 = (const float*)d_in[4];
  const float* cb_ws = (const float*)d_in[5];
  const float* cb_bs = (const float*)d_in[6];
  const float* in_w  = (const float*)d_in[7];
  const float* dw_w  = (const float*)d_in[8];
  const float* dw_b  = (const float*)d_in[9];
  const float* xp_w  = (const float*)d_in[10];
  const float* dtp_w = (const float*)d_in[11];
  const float* dtp_b = (const float*)d_in[12];
  const float* A_logs= (const float*)d_in[13];
  const float* Ds    = (const float*)d_in[14];
  const float* ong   = (const float*)d_in[15];
  const float* onb   = (const float*)d_in[16];
  const float* op_w  = (const float*)d_in[17];
  const float* gn_g  = (const float*)d_in[18];
  const float* gn_b  = (const float*)d_in[19];
  const float* l1_w  = (const float*)d_in[20];
  const float* l1_b  = (const float*)d_in[21];
  const float* l2_w  = (const float*)d_in[22];
  const float* l2_b  = (const float*)d_in[23];
  const float* sh_w  = (const float*)d_in[24];
  const float* sh_b  = (const float*)d_in[25];

  const size_t SZ_X  = (size_t)BB*DMC*LL;       // 1,179,648
  const size_t SZ_XZ = (size_t)BB*2*DIC*LL;     // 4,718,592
  const size_t SZ_XI = (size_t)BB*DIC*LL;       // 2,359,296
  const size_t SZ_XD = (size_t)BB*KD*20*LL;     // 1,310,720
  const size_t SZ_HP = (size_t)BB*KD*NCH*DIC*NS;// 2,359,296

  float* ws = (float*)d_ws;
  size_t off = 0;
  float* x    = ws + off; off += SZ_X;
  float* tmp  = ws + off; off += SZ_X;
  float* xz   = ws + off; off += SZ_XZ;
  float* xi   = ws + off; off += SZ_XI;
  float* xdbl = ws + off; off += SZ_XD;
  float* cumA = ws + off; off += SZ_HP;
  float* hp   = ws + off; off += SZ_HP;
  float* ybuf = ws + off; off += SZ_XI;
  if (ws_size < off*sizeof(float)) return; // not enough scratch; fail loudly

  dim3 blk(256);
  auto nb = [](long n){ return dim3((unsigned)((n + 255)/256)); };

  k_conv1<<<nb((long)BB*DMC*LL), blk, 0, stream>>>(image, cb_w1, cb_b1, tmp);
  k_conv2<<<nb((long)BB*18*LL), blk, 0, stream>>>(tmp, image, cb_w2, cb_b2, cb_ws, cb_bs, x);

  for (int i=0; i<NLAYER; ++i){
    const float* in_w_i  = in_w  + (size_t)i*2*DIC*DMC;
    const float* dw_w_i  = dw_w  + (size_t)i*DIC*9;
    const float* dw_b_i  = dw_b  + (size_t)i*DIC;
    const float* xp_w_i  = xp_w  + (size_t)i*KD*20*DIC;
    const float* dtp_w_i = dtp_w + (size_t)i*KD*DIC*RD;
    const float* dtp_b_i = dtp_b + (size_t)i*KD*DIC;
    const float* alog_i  = A_logs+ (size_t)i*KD*DIC*NS;
    const float* Ds_i    = Ds    + (size_t)i*KD*DIC;
    const float* ong_i   = ong   + (size_t)i*DIC;
    const float* onb_i   = onb   + (size_t)i*DIC;
    const float* op_w_i  = op_w  + (size_t)i*DMC*DIC;
    const float* gn_g_i  = gn_g  + (size_t)i*DMC;
    const float* gn_b_i  = gn_b  + (size_t)i*DMC;
    const float* l1_w_i  = l1_w  + (size_t)i*DMC*DMC;
    const float* l1_b_i  = l1_b  + (size_t)i*DMC;
    const float* l2_w_i  = l2_w  + (size_t)i*DMC*DMC;
    const float* l2_b_i  = l2_b  + (size_t)i*DMC;

    k_xz  <<<nb((long)BB*DMC*LL), blk, 0, stream>>>(x, in_w_i, xz);
    k_dw  <<<nb((long)BB*DIC*LL), blk, 0, stream>>>(xz, dw_w_i, dw_b_i, xi);
    k_xdbl<<<nb((long)BB*KD*LL),  blk, 0, stream>>>(xi, xp_w_i, xdbl);
    k_p1  <<<nb((long)BB*KD*NCH*DIC), blk, 0, stream>>>(xi, xdbl, dtp_w_i, dtp_b_i, alog_i, cumA, hp);
    k_p2  <<<nb((long)BB*KD*DIC), blk, 0, stream>>>(cumA, hp);
    hipMemsetAsync(ybuf, 0, SZ_XI*sizeof(float), stream);
    k_p3  <<<nb((long)BB*KD*NCH*DIC), blk, 0, stream>>>(xi, xdbl, dtp_w_i, dtp_b_i, alog_i, Ds_i, hp, ybuf);
    k_lnz <<<nb((long)BB*LL), blk, 0, stream>>>(ybuf, xz, ong_i, onb_i);
    k_oproj<<<nb((long)BB*18*LL), blk, 0, stream>>>(ybuf, op_w_i, x);
    k_gn  <<<dim3(BB*GRP), blk, 0, stream>>>(x, gn_g_i, gn_b_i);
    k_dense<<<nb((long)BB*18*LL), blk, 0, stream>>>(x, l1_w_i, l1_b_i, tmp, 1);
    k_dense<<<nb((long)BB*18*LL), blk, 0, stream>>>(tmp, l2_w_i, l2_b_i, x, 0);
  }

  k_shrink<<<nb((long)BB*CI*LL), blk, 0, stream>>>(x, sh_w, sh_b, (float*)d_out);
}

// Round 2
// 1054.468 us; speedup vs baseline: 1.9012x; 1.9012x over previous
//
#include <hip/hip_runtime.h>
#include <math.h>

#define BB 4
#define CI 6
#define LL 4096
#define DMC 72
#define DIC 144
#define KD 4
#define NS 8
#define RD 4
#define NLAYER 2
#define GRP 12
#define NCH 128   // chunks per scan
#define TS 32     // steps per chunk

__device__ __forceinline__ float sigmoidf_(float x){ return 1.f/(1.f+__expf(-x)); }
__device__ __forceinline__ float siluf_(float x){ return x*sigmoidf_(x); }
__device__ __forceinline__ float softplusf_(float x){ return fmaxf(x,0.f) + log1pf(__expf(-fabsf(x))); }

// spatial position p (row-major h*64+w) for scan index l of direction k
__device__ __forceinline__ int dirmap(int k, int l){
  switch(k & 3){
    case 0: return l;
    case 1: return ((l & 63) << 6) | (l >> 6);
    case 2: return (LL-1) - l;
    default: { int m = (LL-1) - l; return ((m & 63) << 6) | (m >> 6); }
  }
}

// ---------- conv 6->72 3x3 + lrelu(0.01) ----------
__global__ void k_conv1(const float* __restrict__ img, const float* __restrict__ w,
                        const float* __restrict__ bias, float* __restrict__ out){
  int idx = blockIdx.x*256 + threadIdx.x;
  if (idx >= BB*DMC*LL) return;
  int p = idx & 4095; int o = (idx>>12) % DMC; int b = idx / (DMC*LL);
  int h = p>>6, wx = p&63;
  float acc = bias[o];
  for (int ic=0; ic<CI; ++ic){
    const float* ip = img + ((b*CI+ic)<<12);
    const float* wp = w + (o*CI+ic)*9;
    #pragma unroll
    for (int kh=0; kh<3; ++kh){
      int hy = h+kh-1; if ((unsigned)hy >= 64u) continue;
      #pragma unroll
      for (int kw=0; kw<3; ++kw){
        int wxx = wx+kw-1; if ((unsigned)wxx >= 64u) continue;
        acc += ip[(hy<<6)+wxx]*wp[kh*3+kw];
      }
    }
  }
  out[idx] = acc >= 0.f ? acc : 0.01f*acc;
}

// ---------- conv 72->72 3x3 + 1x1 shortcut + lrelu(0.01), 4 oc/thread ----------
__global__ void k_conv2(const float* __restrict__ hin, const float* __restrict__ img,
                        const float* __restrict__ w2, const float* __restrict__ b2,
                        const float* __restrict__ wsc, const float* __restrict__ bsc,
                        float* __restrict__ xout){
  int idx = blockIdx.x*256 + threadIdx.x;
  if (idx >= BB*18*LL) return;
  int p = idx & 4095; int og = (idx>>12) % 18; int b = idx / (18*LL);
  int h = p>>6, wx = p&63;
  float acc[4];
  #pragma unroll
  for (int j=0;j<4;++j) acc[j] = b2[og*4+j] + bsc[og*4+j];
  for (int ic=0; ic<DMC; ++ic){
    const float* ip = hin + ((b*DMC+ic)<<12);
    const float* wp = w2 + (og*4)*DMC*9 + ic*9;
    #pragma unroll
    for (int kh=0; kh<3; ++kh){
      int hy = h+kh-1; if ((unsigned)hy >= 64u) continue;
      #pragma unroll
      for (int kw=0; kw<3; ++kw){
        int wxx = wx+kw-1; if ((unsigned)wxx >= 64u) continue;
        float v = ip[(hy<<6)+wxx];
        #pragma unroll
        for (int j=0;j<4;++j) acc[j] += v * wp[j*DMC*9 + kh*3+kw];
      }
    }
  }
  for (int ic=0; ic<CI; ++ic){
    float v = img[((b*CI+ic)<<12)+p];
    #pragma unroll
    for (int j=0;j<4;++j) acc[j] += v * wsc[(og*4+j)*CI+ic];
  }
  #pragma unroll
  for (int j=0;j<4;++j){
    float a = acc[j];
    xout[((b*DMC+og*4+j)<<12)+p] = a >= 0.f ? a : 0.01f*a;
  }
}

// ---------- xz: first 144 ch -> xz_lo [b][c][p]; last 144 (z) -> z_t [b][p][c] ----------
__global__ void k_xz(const float* __restrict__ x, const float* __restrict__ inw,
                     float* __restrict__ xz, float* __restrict__ z_t){
  int idx = blockIdx.x*256 + threadIdx.x;
  if (idx >= BB*DMC*LL) return;  // 72 groups of 4 = 288 outputs
  int p = idx & 4095; int eg = (idx>>12) % DMC; int b = idx / (DMC*LL);
  float acc[4] = {0.f,0.f,0.f,0.f};
  for (int c=0; c<DMC; ++c){
    float v = x[((b*DMC+c)<<12)+p];
    #pragma unroll
    for (int j=0;j<4;++j) acc[j] += v * inw[(eg*4+j)*DMC + c];
  }
  if (eg < 36){
    #pragma unroll
    for (int j=0;j<4;++j) xz[((b*DIC+eg*4+j)<<12)+p] = acc[j];
  } else {
    float4 v4 = make_float4(acc[0],acc[1],acc[2],acc[3]);
    *(float4*)(z_t + ((size_t)b*LL+p)*DIC + (eg*4-DIC)) = v4;
  }
}

// ---------- depthwise 3x3 + bias + silu -> xi_t [b][p][c] ----------
__global__ void k_dw(const float* __restrict__ xz, const float* __restrict__ dww,
                     const float* __restrict__ dwb, float* __restrict__ xi_t){
  int idx = blockIdx.x*256 + threadIdx.x;
  if (idx >= BB*DIC*LL) return;
  int p = idx & 4095; int c = (idx>>12) % DIC; int b = idx / (DIC*LL);
  int h = p>>6, wx = p&63;
  const float* ip = xz + ((size_t)(b*DIC+c)<<12);
  const float* wp = dww + c*9;
  float acc = dwb[c];
  #pragma unroll
  for (int kh=0; kh<3; ++kh){
    int hy = h+kh-1; if ((unsigned)hy >= 64u) continue;
    #pragma unroll
    for (int kw=0; kw<3; ++kw){
      int wxx = wx+kw-1; if ((unsigned)wxx >= 64u) continue;
      acc += ip[(hy<<6)+wxx]*wp[kh*3+kw];
    }
  }
  xi_t[((size_t)b*LL+p)*DIC + c] = siluf_(acc);
}

// ---------- x_dbl[b,k,c20,l], thread per (b,k,l,half-of-20) ----------
__global__ void k_xdbl(const float* __restrict__ xi_t, const float* __restrict__ xpw,
                       float* __restrict__ xdbl){
  int idx = blockIdx.x*256 + threadIdx.x;
  if (idx >= BB*KD*LL*2) return;
  int l = idx & 4095; int k = (idx>>12) & 3; int r = idx>>14; int b = r & 3; int half = r>>2;
  int p = dirmap(k,l);
  const float* xib = xi_t + ((size_t)b*LL + p)*DIC;
  const float* wp = xpw + k*20*DIC + half*10*DIC;
  float acc[10];
  #pragma unroll
  for (int c=0;c<10;++c) acc[c]=0.f;
  for (int d=0; d<DIC; d+=4){
    float4 v = *(const float4*)(xib + d);
    #pragma unroll
    for (int c=0;c<10;++c){
      acc[c] += v.x*wp[c*DIC+d] + v.y*wp[c*DIC+d+1] + v.z*wp[c*DIC+d+2] + v.w*wp[c*DIC+d+3];
    }
  }
  #pragma unroll
  for (int c=0;c<10;++c) xdbl[((size_t)(b*KD+k)*20 + half*10 + c)*LL + l] = acc[c];
}

__device__ __forceinline__ void scan_decode(int idx, int& b, int& k, int& ch, int& c){
  c = idx % DIC;
  int r = idx / DIC;
  ch = r % NCH;
  r /= NCH;
  k = r & 3; b = r >> 2;
}

// ---------- P1: per-chunk summaries (cumA, partial state), layout [bk][ch][n][c] ----------
__global__ void k_p1(const float* __restrict__ xi_t, const float* __restrict__ xdbl,
                     const float* __restrict__ dtpw, const float* __restrict__ dtpb,
                     const float* __restrict__ alog,
                     float* __restrict__ cumA, float* __restrict__ hp){
  int idx = blockIdx.x*256 + threadIdx.x;
  if (idx >= BB*KD*NCH*DIC) return;
  int b,k,ch,c; scan_decode(idx,b,k,ch,c);
  float Arow[NS];
  #pragma unroll
  for (int n=0;n<NS;++n) Arow[n] = -__expf(alog[(k*DIC+c)*NS+n]);
  float wdt[RD];
  #pragma unroll
  for (int r=0;r<RD;++r) wdt[r] = dtpw[(k*DIC+c)*RD+r];
  float bdt = dtpb[k*DIC+c];
  const float* xd = xdbl + (size_t)(b*KD+k)*20*LL;
  const float* xib = xi_t + (size_t)b*LL*DIC + c;
  float h[NS];
  #pragma unroll
  for (int n=0;n<NS;++n) h[n]=0.f;
  float sumd = 0.f;
  for (int t=0; t<TS; ++t){
    int l = ch*TS + t;
    float dt = bdt;
    #pragma unroll
    for (int r=0;r<RD;++r) dt += xd[r*LL + l]*wdt[r];
    dt = softplusf_(dt);
    sumd += dt;
    float u = xib[(size_t)dirmap(k,l)*DIC];
    float du = dt*u;
    #pragma unroll
    for (int n=0;n<NS;++n){
      float Bn = xd[(RD+n)*LL + l];
      h[n] = h[n]*__expf(dt*Arow[n]) + du*Bn;
    }
  }
  size_t base = ((size_t)((b*KD+k)*NCH + ch)*NS)*DIC + c;
  #pragma unroll
  for (int n=0;n<NS;++n) hp[base + n*DIC] = h[n];
  #pragma unroll
  for (int n=0;n<NS;++n) cumA[base + n*DIC] = __expf(sumd*Arow[n]);
}

// ---------- P2: prefix over chunk summaries, thread per (bk,n,c); hp becomes h_in ----------
__global__ void k_p2(const float* __restrict__ cumA, float* __restrict__ hp){
  int idx = blockIdx.x*256 + threadIdx.x;
  if (idx >= BB*KD*NS*DIC) return;
  int c = idx % DIC; int n = (idx/DIC) % NS; int bk = idx/(DIC*NS);
  float h = 0.f;
  for (int ch=0; ch<NCH; ++ch){
    size_t base = ((size_t)(bk*NCH+ch)*NS + n)*DIC + c;
    float a = cumA[base];
    float pp = hp[base];
    hp[base] = h;
    h = a*h + pp;
  }
}

// ---------- P3: replay chunks, accumulate into y_t [b][p][c] with coalesced atomics ----------
__global__ void k_p3(const float* __restrict__ xi_t, const float* __restrict__ xdbl,
                     const float* __restrict__ dtpw, const float* __restrict__ dtpb,
                     const float* __restrict__ alog, const float* __restrict__ Dsv,
                     const float* __restrict__ hin, float* __restrict__ y_t){
  int idx = blockIdx.x*256 + threadIdx.x;
  if (idx >= BB*KD*NCH*DIC) return;
  int b,k,ch,c; scan_decode(idx,b,k,ch,c);
  float Arow[NS];
  #pragma unroll
  for (int n=0;n<NS;++n) Arow[n] = -__expf(alog[(k*DIC+c)*NS+n]);
  float wdt[RD];
  #pragma unroll
  for (int r=0;r<RD;++r) wdt[r] = dtpw[(k*DIC+c)*RD+r];
  float bdt = dtpb[k*DIC+c];
  float Dv = Dsv[k*DIC+c];
  const float* xd = xdbl + (size_t)(b*KD+k)*20*LL;
  const float* xib = xi_t + (size_t)b*LL*DIC + c;
  float* yb = y_t + (size_t)b*LL*DIC + c;
  float h[NS];
  size_t base = ((size_t)((b*KD+k)*NCH + ch)*NS)*DIC + c;
  #pragma unroll
  for (int n=0;n<NS;++n) h[n] = hin[base + n*DIC];
  for (int t=0; t<TS; ++t){
    int l = ch*TS + t;
    float dt = bdt;
    #pragma unroll
    for (int r=0;r<RD;++r) dt += xd[r*LL + l]*wdt[r];
    dt = softplusf_(dt);
    int p = dirmap(k,l);
    float u = xib[(size_t)p*DIC];
    float du = dt*u;
    float y = 0.f;
    #pragma unroll
    for (int n=0;n<NS;++n){
      h[n] = h[n]*__expf(dt*Arow[n]) + du*xd[(RD+n)*LL + l];
      y += h[n]*xd[(RD+NS+n)*LL + l];
    }
    y += u*Dv;
    atomicAdd(yb + (size_t)p*DIC, y);
  }
}

// ---------- LN over c per pixel (wave-per-pixel), * ong+onb, * silu(z); in place ----------
__global__ void k_lnz(float* __restrict__ y_t, const float* __restrict__ z_t,
                      const float* __restrict__ ong, const float* __restrict__ onb){
  int gid = blockIdx.x*256 + threadIdx.x;
  int wid = gid >> 6;
  int lane = gid & 63;
  if (wid >= BB*LL) return;
  size_t rb = (size_t)wid * DIC;
  float v0 = y_t[rb + lane];
  float v1 = y_t[rb + 64 + lane];
  float v2 = (lane < 16) ? y_t[rb + 128 + lane] : 0.f;
  float s = v0 + v1 + v2;
  float q = v0*v0 + v1*v1 + v2*v2;
  #pragma unroll
  for (int o=32; o>0; o>>=1){ s += __shfl_xor(s,o,64); q += __shfl_xor(q,o,64); }
  float mu = s*(1.f/DIC);
  float var = q*(1.f/DIC) - mu*mu;
  float rs = rsqrtf(var + 1e-5f);
  float z0 = z_t[rb + lane];
  y_t[rb + lane] = ((v0-mu)*rs*ong[lane] + onb[lane]) * siluf_(z0);
  float z1 = z_t[rb + 64 + lane];
  y_t[rb + 64 + lane] = ((v1-mu)*rs*ong[64+lane] + onb[64+lane]) * siluf_(z1);
  if (lane < 16){
    float z2 = z_t[rb + 128 + lane];
    y_t[rb + 128 + lane] = ((v2-mu)*rs*ong[128+lane] + onb[128+lane]) * siluf_(z2);
  }
}

// ---------- out-proj 72 = op_w(72x144) . y_t, og-fastest for broadcast y reads ----------
__global__ void k_oproj(const float* __restrict__ y_t, const float* __restrict__ opw,
                        float* __restrict__ xout){
  int idx = blockIdx.x*256 + threadIdx.x;
  if (idx >= BB*LL*18) return;
  int og = idx % 18; int rest = idx/18; int p = rest & 4095; int b = rest >> 12;
  const float* yb = y_t + ((size_t)b*LL + p)*DIC;
  float acc[4] = {0.f,0.f,0.f,0.f};
  for (int d=0; d<DIC; d+=4){
    float4 v = *(const float4*)(yb + d);
    #pragma unroll
    for (int j=0;j<4;++j){
      const float* w = opw + (og*4+j)*DIC + d;
      acc[j] += v.x*w[0] + v.y*w[1] + v.z*w[2] + v.w*w[3];
    }
  }
  #pragma unroll
  for (int j=0;j<4;++j) xout[((size_t)(b*DMC+og*4+j)<<12)+p] = acc[j];
}

// ---------- groupnorm (12 groups of 6ch) in place ----------
__global__ void k_gn(float* __restrict__ x, const float* __restrict__ g,
                     const float* __restrict__ bta){
  __shared__ float s1[256], s2[256];
  int b = blockIdx.x / GRP; int gr = blockIdx.x % GRP;
  const int CG = DMC/GRP; // 6
  float ls=0.f, lq=0.f;
  for (int i = threadIdx.x; i < CG*LL; i += 256){
    int c = gr*CG + (i>>12); int p = i & 4095;
    float v = x[((size_t)(b*DMC+c)<<12)+p];
    ls += v; lq += v*v;
  }
  s1[threadIdx.x]=ls; s2[threadIdx.x]=lq; __syncthreads();
  for (int s=128; s>0; s>>=1){
    if (threadIdx.x < s){ s1[threadIdx.x]+=s1[threadIdx.x+s]; s2[threadIdx.x]+=s2[threadIdx.x+s]; }
    __syncthreads();
  }
  float mu = s1[0]/(CG*LL);
  float var = s2[0]/(CG*LL) - mu*mu;
  float rs = rsqrtf(var + 1e-5f);
  for (int i = threadIdx.x; i < CG*LL; i += 256){
    int c = gr*CG + (i>>12); int p = i & 4095;
    size_t off = ((size_t)(b*DMC+c)<<12)+p;
    x[off] = (x[off]-mu)*rs*g[c] + bta[c];
  }
}

// ---------- dense 72x72 + bias (+ optional lrelu 0.04), 4 oc/thread ----------
__global__ void k_dense(const float* __restrict__ xin, const float* __restrict__ w,
                        const float* __restrict__ bias, float* __restrict__ xout,
                        int do_lrelu){
  int idx = blockIdx.x*256 + threadIdx.x;
  if (idx >= BB*18*LL) return;
  int p = idx & 4095; int og = (idx>>12) % 18; int b = idx / (18*LL);
  float acc[4];
  #pragma unroll
  for (int j=0;j<4;++j) acc[j] = bias[og*4+j];
  for (int c=0; c<DMC; ++c){
    float v = xin[((size_t)(b*DMC+c)<<12)+p];
    #pragma unroll
    for (int j=0;j<4;++j) acc[j] += v * w[(og*4+j)*DMC + c];
  }
  #pragma unroll
  for (int j=0;j<4;++j){
    float a = acc[j];
    if (do_lrelu) a = a >= 0.f ? a : 0.04f*a;
    xout[((size_t)(b*DMC+og*4+j)<<12)+p] = a;
  }
}

// ---------- shrink conv 72->6 3x3 + sigmoid ----------
__global__ void k_shrink(const float* __restrict__ x, const float* __restrict__ w,
                         const float* __restrict__ bias, float* __restrict__ out){
  int idx = blockIdx.x*256 + threadIdx.x;
  if (idx >= BB*CI*LL) return;
  int p = idx & 4095; int o = (idx>>12) % CI; int b = idx / (CI*LL);
  int h = p>>6, wx = p&63;
  float acc = bias[o];
  for (int ic=0; ic<DMC; ++ic){
    const float* ip = x + ((size_t)(b*DMC+ic)<<12);
    const float* wp = w + (o*DMC+ic)*9;
    #pragma unroll
    for (int kh=0; kh<3; ++kh){
      int hy = h+kh-1; if ((unsigned)hy >= 64u) continue;
      #pragma unroll
      for (int kw=0; kw<3; ++kw){
        int wxx = wx+kw-1; if ((unsigned)wxx >= 64u) continue;
        acc += ip[(hy<<6)+wxx]*wp[kh*3+kw];
      }
    }
  }
  out[idx] = sigmoidf_(acc);
}

extern "C" void kernel_launch(void* const* d_in, const int* in_sizes, int n_in,
                              void* d_out, int out_size, void* d_ws, size_t ws_size,
                              hipStream_t stream){
  const float* image = (const float*)d_in[0];
  const float* cb_w1 = (const float*)d_in[1];
  const float* cb_b1 = (const float*)d_in[2];
  const float* cb_w2 = (const float*)d_in[3];
  const float* cb_b2 = (const float*)d_in[4];
  const float* cb_ws = (const float*)d_in[5];
  const float* cb_bs = (const float*)d_in[6];
  const float* in_w  = (const float*)d_in[7];
  const float* dw_w  = (const float*)d_in[8];
  const float* dw_b  = (const float*)d_in[9];
  const float* xp_w  = (const float*)d_in[10];
  const float* dtp_w = (const float*)d_in[11];
  const float* dtp_b = (const float*)d_in[12];
  const float* A_logs= (const float*)d_in[13];
  const float* Ds    = (const float*)d_in[14];
  const float* ong   = (const float*)d_in[15];
  const float* onb   = (const float*)d_in[16];
  const float* op_w  = (const float*)d_in[17];
  const float* gn_g  = (const float*)d_in[18];
  const float* gn_b  = (const float*)d_in[19];
  const float* l1_w  = (const float*)d_in[20];
  const float* l1_b  = (const float*)d_in[21];
  const float* l2_w  = (const float*)d_in[22];
  const float* l2_b  = (const float*)d_in[23];
  const float* sh_w  = (const float*)d_in[24];
  const float* sh_b  = (const float*)d_in[25];

  const size_t SZ_X  = (size_t)BB*DMC*LL;       // 1,179,648
  const size_t SZ_C  = (size_t)BB*DIC*LL;       // 2,359,296
  const size_t SZ_XD = (size_t)BB*KD*20*LL;     // 1,310,720
  const size_t SZ_HP = (size_t)BB*KD*NCH*NS*DIC;// 2,359,296

  float* ws = (float*)d_ws;
  size_t off = 0;
  float* x    = ws + off; off += SZ_X;
  float* tmp  = ws + off; off += SZ_X;
  float* xz   = ws + off; off += SZ_C;   // lower 144 channels, [b][c][p]
  float* z_t  = ws + off; off += SZ_C;   // z, [b][p][c]
  float* xi_t = ws + off; off += SZ_C;   // [b][p][c]
  float* xdbl = ws + off; off += SZ_XD;
  float* cumA = ws + off; off += SZ_HP;
  float* hp   = ws + off; off += SZ_HP;
  float* y_t  = ws + off; off += SZ_C;   // [b][p][c]
  if (ws_size < off*sizeof(float)) return;

  dim3 blk(256);
  auto nb = [](long n){ return dim3((unsigned)((n + 255)/256)); };

  k_conv1<<<nb((long)BB*DMC*LL), blk, 0, stream>>>(image, cb_w1, cb_b1, tmp);
  k_conv2<<<nb((long)BB*18*LL), blk, 0, stream>>>(tmp, image, cb_w2, cb_b2, cb_ws, cb_bs, x);

  for (int i=0; i<NLAYER; ++i){
    const float* in_w_i  = in_w  + (size_t)i*2*DIC*DMC;
    const float* dw_w_i  = dw_w  + (size_t)i*DIC*9;
    const float* dw_b_i  = dw_b  + (size_t)i*DIC;
    const float* xp_w_i  = xp_w  + (size_t)i*KD*20*DIC;
    const float* dtp_w_i = dtp_w + (size_t)i*KD*DIC*RD;
    const float* dtp_b_i = dtp_b + (size_t)i*KD*DIC;
    const float* alog_i  = A_logs+ (size_t)i*KD*DIC*NS;
    const float* Ds_i    = Ds    + (size_t)i*KD*DIC;
    const float* ong_i   = ong   + (size_t)i*DIC;
    const float* onb_i   = onb   + (size_t)i*DIC;
    const float* op_w_i  = op_w  + (size_t)i*DMC*DIC;
    const float* gn_g_i  = gn_g  + (size_t)i*DMC;
    const float* gn_b_i  = gn_b  + (size_t)i*DMC;
    const float* l1_w_i  = l1_w  + (size_t)i*DMC*DMC;
    const float* l1_b_i  = l1_b  + (size_t)i*DMC;
    const float* l2_w_i  = l2_w  + (size_t)i*DMC*DMC;
    const float* l2_b_i  = l2_b  + (size_t)i*DMC;

    k_xz  <<<nb((long)BB*DMC*LL), blk, 0, stream>>>(x, in_w_i, xz, z_t);
    k_dw  <<<nb((long)BB*DIC*LL), blk, 0, stream>>>(xz, dw_w_i, dw_b_i, xi_t);
    k_xdbl<<<nb((long)BB*KD*LL*2),blk, 0, stream>>>(xi_t, xp_w_i, xdbl);
    k_p1  <<<nb((long)BB*KD*NCH*DIC), blk, 0, stream>>>(xi_t, xdbl, dtp_w_i, dtp_b_i, alog_i, cumA, hp);
    k_p2  <<<nb((long)BB*KD*NS*DIC), blk, 0, stream>>>(cumA, hp);
    hipMemsetAsync(y_t, 0, SZ_C*sizeof(float), stream);
    k_p3  <<<nb((long)BB*KD*NCH*DIC), blk, 0, stream>>>(xi_t, xdbl, dtp_w_i, dtp_b_i, alog_i, Ds_i, hp, y_t);
    k_lnz <<<nb((long)BB*LL*64), blk, 0, stream>>>(y_t, z_t, ong_i, onb_i);
    k_oproj<<<nb((long)BB*LL*18), blk, 0, stream>>>(y_t, op_w_i, x);
    k_gn  <<<dim3(BB*GRP), blk, 0, stream>>>(x, gn_g_i, gn_b_i);
    k_dense<<<nb((long)BB*18*LL), blk, 0, stream>>>(x, l1_w_i, l1_b_i, tmp, 1);
    k_dense<<<nb((long)BB*18*LL), blk, 0, stream>>>(tmp, l2_w_i, l2_b_i, x, 0);
  }

  k_shrink<<<nb((long)BB*CI*LL), blk, 0, stream>>>(x, sh_w, sh_b, (float*)d_out);
}

// Round 3
// 1027.724 us; speedup vs baseline: 1.9506x; 1.0260x over previous
//
#include <hip/hip_runtime.h>
#include <math.h>

#define BB 4
#define CI 6
#define LL 4096
#define DMC 72
#define DIC 144
#define KD 4
#define NS 8
#define RD 4
#define NLAYER 2
#define GRP 12
#define NCH 128   // chunks per scan
#define TS 32     // steps per chunk

__device__ __forceinline__ float sigmoidf_(float x){ return 1.f/(1.f+__expf(-x)); }
__device__ __forceinline__ float siluf_(float x){ return x*sigmoidf_(x); }
__device__ __forceinline__ float softplusf_(float x){ return fmaxf(x,0.f) + log1pf(__expf(-fabsf(x))); }

// spatial position p (row-major h*64+w) for scan index l of direction k
__device__ __forceinline__ int dirmap(int k, int l){
  switch(k & 3){
    case 0: return l;
    case 1: return ((l & 63) << 6) | (l >> 6);
    case 2: return (LL-1) - l;
    default: { int m = (LL-1) - l; return ((m & 63) << 6) | (m >> 6); }
  }
}

__device__ __forceinline__ void gather9(const float* __restrict__ ip, int h, int wx, float a[9]){
  #pragma unroll
  for (int kh=0; kh<3; ++kh){
    int hy = h+kh-1;
    bool okh = (unsigned)hy < 64u;
    int rb = hy<<6;
    #pragma unroll
    for (int kw=0; kw<3; ++kw){
      int wxx = wx+kw-1;
      a[kh*3+kw] = (okh && (unsigned)wxx < 64u) ? ip[rb+wxx] : 0.f;
    }
  }
}

// ---------- conv 6->72 3x3 + lrelu(0.01) ----------
__global__ void k_conv1(const float* __restrict__ img, const float* __restrict__ w,
                        const float* __restrict__ bias, float* __restrict__ out){
  int idx = blockIdx.x*256 + threadIdx.x;
  if (idx >= BB*DMC*LL) return;
  int p = idx & 4095; int o = (idx>>12) % DMC; int b = idx / (DMC*LL);
  int h = p>>6, wx = p&63;
  float acc = bias[o];
  #pragma unroll 2
  for (int ic=0; ic<CI; ++ic){
    const float* ip = img + ((b*CI+ic)<<12);
    const float* wp = w + (o*CI+ic)*9;
    float a[9]; gather9(ip, h, wx, a);
    float wv[9];
    #pragma unroll
    for (int t=0;t<9;++t) wv[t] = wp[t];
    float s = 0.f;
    #pragma unroll
    for (int t=0;t<9;++t) s += a[t]*wv[t];
    acc += s;
  }
  out[idx] = acc >= 0.f ? acc : 0.01f*acc;
}

// ---------- conv 72->72 3x3 + 1x1 shortcut + lrelu(0.01), 4 oc/thread ----------
__global__ void k_conv2(const float* __restrict__ hin, const float* __restrict__ img,
                        const float* __restrict__ w2, const float* __restrict__ b2,
                        const float* __restrict__ wsc, const float* __restrict__ bsc,
                        float* __restrict__ xout){
  int idx = blockIdx.x*256 + threadIdx.x;
  if (idx >= BB*18*LL) return;
  int p = idx & 4095; int og = (idx>>12) % 18; int b = idx / (18*LL);
  int h = p>>6, wx = p&63;
  float acc[4];
  #pragma unroll
  for (int j=0;j<4;++j) acc[j] = b2[og*4+j] + bsc[og*4+j];
  const float* ipb = hin + ((size_t)b*DMC<<12);
  const float* wb  = w2 + (size_t)(og*4)*DMC*9;
  #pragma unroll 2
  for (int ic=0; ic<DMC; ++ic){
    const float* ip = ipb + (ic<<12);
    float a[9]; gather9(ip, h, wx, a);
    const float* wp = wb + ic*9;
    float wv[4][9];
    #pragma unroll
    for (int j=0;j<4;++j){
      #pragma unroll
      for (int t=0;t<9;++t) wv[j][t] = wp[(size_t)j*DMC*9 + t];
    }
    #pragma unroll
    for (int j=0;j<4;++j){
      float s = 0.f;
      #pragma unroll
      for (int t=0;t<9;++t) s += a[t]*wv[j][t];
      acc[j] += s;
    }
  }
  #pragma unroll 2
  for (int ic=0; ic<CI; ++ic){
    float v = img[((b*CI+ic)<<12)+p];
    #pragma unroll
    for (int j=0;j<4;++j) acc[j] += v * wsc[(og*4+j)*CI+ic];
  }
  #pragma unroll
  for (int j=0;j<4;++j){
    float a = acc[j];
    xout[((b*DMC+og*4+j)<<12)+p] = a >= 0.f ? a : 0.01f*a;
  }
}

// ---------- xz: first 144 ch -> xz_lo [b][c][p]; last 144 (z) -> z_t [b][p][c] ----------
__global__ void k_xz(const float* __restrict__ x, const float* __restrict__ inw,
                     float* __restrict__ xz, float* __restrict__ z_t){
  int idx = blockIdx.x*256 + threadIdx.x;
  if (idx >= BB*DMC*LL) return;  // 72 groups of 4 = 288 outputs
  int p = idx & 4095; int eg = (idx>>12) % DMC; int b = idx / (DMC*LL);
  float acc[4] = {0.f,0.f,0.f,0.f};
  for (int c0=0; c0<DMC; c0+=8){
    float a[8];
    #pragma unroll
    for (int q=0;q<8;++q) a[q] = x[((b*DMC+c0+q)<<12)+p];
    #pragma unroll
    for (int j=0;j<4;++j){
      const float* w = inw + (eg*4+j)*DMC + c0;
      float4 w0 = *(const float4*)(w);
      float4 w1 = *(const float4*)(w+4);
      acc[j] += a[0]*w0.x + a[1]*w0.y + a[2]*w0.z + a[3]*w0.w
              + a[4]*w1.x + a[5]*w1.y + a[6]*w1.z + a[7]*w1.w;
    }
  }
  if (eg < 36){
    #pragma unroll
    for (int j=0;j<4;++j) xz[((b*DIC+eg*4+j)<<12)+p] = acc[j];
  } else {
    float4 v4 = make_float4(acc[0],acc[1],acc[2],acc[3]);
    *(float4*)(z_t + ((size_t)b*LL+p)*DIC + (eg*4-DIC)) = v4;
  }
}

// ---------- depthwise 3x3 + bias + silu -> xi_t [b][p][c] ----------
__global__ void k_dw(const float* __restrict__ xz, const float* __restrict__ dww,
                     const float* __restrict__ dwb, float* __restrict__ xi_t){
  int idx = blockIdx.x*256 + threadIdx.x;
  if (idx >= BB*DIC*LL) return;
  int p = idx & 4095; int c = (idx>>12) % DIC; int b = idx / (DIC*LL);
  int h = p>>6, wx = p&63;
  const float* ip = xz + ((size_t)(b*DIC+c)<<12);
  const float* wp = dww + c*9;
  float a[9]; gather9(ip, h, wx, a);
  float wv[9];
  #pragma unroll
  for (int t=0;t<9;++t) wv[t] = wp[t];
  float acc = dwb[c];
  #pragma unroll
  for (int t=0;t<9;++t) acc += a[t]*wv[t];
  xi_t[((size_t)b*LL+p)*DIC + c] = siluf_(acc);
}

// ---------- x_dbl: one act row serves all 4 directions; thread=(b,p,part of 5ch) ----------
__global__ void k_xdbl(const float* __restrict__ xi_t, const float* __restrict__ xpw,
                       float* __restrict__ xdbl){
  int idx = blockIdx.x*256 + threadIdx.x;
  if (idx >= BB*LL*4) return;
  int part = idx & 3; int p = (idx>>2) & 4095; int b = idx >> 14;
  int lk[4];
  lk[0] = p;
  lk[1] = ((p & 63) << 6) | (p >> 6);
  lk[2] = (LL-1) - p;
  lk[3] = (LL-1) - lk[1];
  const float* xib = xi_t + ((size_t)b*LL + p)*DIC;
  float acc[4][5];
  #pragma unroll
  for (int k=0;k<4;++k)
    #pragma unroll
    for (int c=0;c<5;++c) acc[k][c]=0.f;
  for (int d=0; d<DIC; d+=4){
    float4 v = *(const float4*)(xib + d);
    #pragma unroll
    for (int k=0;k<4;++k){
      const float* wk = xpw + (size_t)k*20*DIC + (size_t)part*5*DIC + d;
      #pragma unroll
      for (int c=0;c<5;++c){
        float4 w = *(const float4*)(wk + (size_t)c*DIC);
        acc[k][c] += v.x*w.x + v.y*w.y + v.z*w.z + v.w*w.w;
      }
    }
  }
  #pragma unroll
  for (int k=0;k<4;++k){
    #pragma unroll
    for (int c=0;c<5;++c)
      xdbl[((size_t)(b*KD+k)*20 + part*5 + c)*LL + lk[k]] = acc[k][c];
  }
}

__device__ __forceinline__ void scan_decode(int idx, int& b, int& k, int& ch, int& c){
  c = idx % DIC;
  int r = idx / DIC;
  ch = r % NCH;
  r /= NCH;
  k = r & 3; b = r >> 2;
}

// ---------- P1: per-chunk summaries (cumA, partial state), layout [bk][ch][n][c] ----------
__global__ void k_p1(const float* __restrict__ xi_t, const float* __restrict__ xdbl,
                     const float* __restrict__ dtpw, const float* __restrict__ dtpb,
                     const float* __restrict__ alog,
                     float* __restrict__ cumA, float* __restrict__ hp){
  int idx = blockIdx.x*256 + threadIdx.x;
  if (idx >= BB*KD*NCH*DIC) return;
  int b,k,ch,c; scan_decode(idx,b,k,ch,c);
  float Arow[NS];
  #pragma unroll
  for (int n=0;n<NS;++n) Arow[n] = -__expf(alog[(k*DIC+c)*NS+n]);
  float wdt[RD];
  #pragma unroll
  for (int r=0;r<RD;++r) wdt[r] = dtpw[(k*DIC+c)*RD+r];
  float bdt = dtpb[k*DIC+c];
  const float* xd = xdbl + (size_t)(b*KD+k)*20*LL;
  const float* xib = xi_t + (size_t)b*LL*DIC + c;
  float h[NS];
  #pragma unroll
  for (int n=0;n<NS;++n) h[n]=0.f;
  float sumd = 0.f;
  #pragma unroll 2
  for (int t=0; t<TS; ++t){
    int l = ch*TS + t;
    float din[RD];
    #pragma unroll
    for (int r=0;r<RD;++r) din[r] = xd[r*LL + l];
    float Bv[NS];
    #pragma unroll
    for (int n=0;n<NS;++n) Bv[n] = xd[(RD+n)*LL + l];
    float u = xib[(size_t)dirmap(k,l)*DIC];
    float dt = bdt;
    #pragma unroll
    for (int r=0;r<RD;++r) dt += din[r]*wdt[r];
    dt = softplusf_(dt);
    sumd += dt;
    float du = dt*u;
    #pragma unroll
    for (int n=0;n<NS;++n)
      h[n] = h[n]*__expf(dt*Arow[n]) + du*Bv[n];
  }
  size_t base = ((size_t)((b*KD+k)*NCH + ch)*NS)*DIC + c;
  #pragma unroll
  for (int n=0;n<NS;++n) hp[base + n*DIC] = h[n];
  #pragma unroll
  for (int n=0;n<NS;++n) cumA[base + n*DIC] = __expf(sumd*Arow[n]);
}

// ---------- P2: prefix over chunk summaries, thread per (bk,n,c); hp becomes h_in ----------
__global__ void k_p2(const float* __restrict__ cumA, float* __restrict__ hp){
  int idx = blockIdx.x*256 + threadIdx.x;
  if (idx >= BB*KD*NS*DIC) return;
  int c = idx % DIC; int n = (idx/DIC) % NS; int bk = idx/(DIC*NS);
  float h = 0.f;
  #pragma unroll 4
  for (int ch=0; ch<NCH; ++ch){
    size_t base = ((size_t)(bk*NCH+ch)*NS + n)*DIC + c;
    float a = cumA[base];
    float pp = hp[base];
    hp[base] = h;
    h = a*h + pp;
  }
}

// ---------- P3: replay chunks, accumulate into y_t [b][p][c] with coalesced atomics ----------
__global__ void k_p3(const float* __restrict__ xi_t, const float* __restrict__ xdbl,
                     const float* __restrict__ dtpw, const float* __restrict__ dtpb,
                     const float* __restrict__ alog, const float* __restrict__ Dsv,
                     const float* __restrict__ hin, float* __restrict__ y_t){
  int idx = blockIdx.x*256 + threadIdx.x;
  if (idx >= BB*KD*NCH*DIC) return;
  int b,k,ch,c; scan_decode(idx,b,k,ch,c);
  float Arow[NS];
  #pragma unroll
  for (int n=0;n<NS;++n) Arow[n] = -__expf(alog[(k*DIC+c)*NS+n]);
  float wdt[RD];
  #pragma unroll
  for (int r=0;r<RD;++r) wdt[r] = dtpw[(k*DIC+c)*RD+r];
  float bdt = dtpb[k*DIC+c];
  float Dv = Dsv[k*DIC+c];
  const float* xd = xdbl + (size_t)(b*KD+k)*20*LL;
  const float* xib = xi_t + (size_t)b*LL*DIC + c;
  float* yb = y_t + (size_t)b*LL*DIC + c;
  float h[NS];
  size_t base = ((size_t)((b*KD+k)*NCH + ch)*NS)*DIC + c;
  #pragma unroll
  for (int n=0;n<NS;++n) h[n] = hin[base + n*DIC];
  #pragma unroll 2
  for (int t=0; t<TS; ++t){
    int l = ch*TS + t;
    float din[RD];
    #pragma unroll
    for (int r=0;r<RD;++r) din[r] = xd[r*LL + l];
    float Bv[NS], Cv[NS];
    #pragma unroll
    for (int n=0;n<NS;++n) Bv[n] = xd[(RD+n)*LL + l];
    #pragma unroll
    for (int n=0;n<NS;++n) Cv[n] = xd[(RD+NS+n)*LL + l];
    int p = dirmap(k,l);
    float u = xib[(size_t)p*DIC];
    float dt = bdt;
    #pragma unroll
    for (int r=0;r<RD;++r) dt += din[r]*wdt[r];
    dt = softplusf_(dt);
    float du = dt*u;
    float y = 0.f;
    #pragma unroll
    for (int n=0;n<NS;++n){
      h[n] = h[n]*__expf(dt*Arow[n]) + du*Bv[n];
      y += h[n]*Cv[n];
    }
    y += u*Dv;
    atomicAdd(yb + (size_t)p*DIC, y);
  }
}

// ---------- LN over c per pixel (wave-per-pixel), * ong+onb, * silu(z); in place ----------
__global__ void k_lnz(float* __restrict__ y_t, const float* __restrict__ z_t,
                      const float* __restrict__ ong, const float* __restrict__ onb){
  int gid = blockIdx.x*256 + threadIdx.x;
  int wid = gid >> 6;
  int lane = gid & 63;
  if (wid >= BB*LL) return;
  size_t rb = (size_t)wid * DIC;
  float v0 = y_t[rb + lane];
  float v1 = y_t[rb + 64 + lane];
  float v2 = (lane < 16) ? y_t[rb + 128 + lane] : 0.f;
  float s = v0 + v1 + v2;
  float q = v0*v0 + v1*v1 + v2*v2;
  #pragma unroll
  for (int o=32; o>0; o>>=1){ s += __shfl_xor(s,o,64); q += __shfl_xor(q,o,64); }
  float mu = s*(1.f/DIC);
  float var = q*(1.f/DIC) - mu*mu;
  float rs = rsqrtf(var + 1e-5f);
  float z0 = z_t[rb + lane];
  y_t[rb + lane] = ((v0-mu)*rs*ong[lane] + onb[lane]) * siluf_(z0);
  float z1 = z_t[rb + 64 + lane];
  y_t[rb + 64 + lane] = ((v1-mu)*rs*ong[64+lane] + onb[64+lane]) * siluf_(z1);
  if (lane < 16){
    float z2 = z_t[rb + 128 + lane];
    y_t[rb + 128 + lane] = ((v2-mu)*rs*ong[128+lane] + onb[128+lane]) * siluf_(z2);
  }
}

// ---------- out-proj 72 = op_w(72x144) . y_t, og-fastest for broadcast y reads ----------
__global__ void k_oproj(const float* __restrict__ y_t, const float* __restrict__ opw,
                        float* __restrict__ xout){
  int idx = blockIdx.x*256 + threadIdx.x;
  if (idx >= BB*LL*18) return;
  int og = idx % 18; int rest = idx/18; int p = rest & 4095; int b = rest >> 12;
  const float* yb = y_t + ((size_t)b*LL + p)*DIC;
  float acc[4] = {0.f,0.f,0.f,0.f};
  for (int d=0; d<DIC; d+=8){
    float4 v0 = *(const float4*)(yb + d);
    float4 v1 = *(const float4*)(yb + d + 4);
    #pragma unroll
    for (int j=0;j<4;++j){
      const float* w = opw + (og*4+j)*DIC + d;
      float4 w0 = *(const float4*)(w);
      float4 w1 = *(const float4*)(w+4);
      acc[j] += v0.x*w0.x + v0.y*w0.y + v0.z*w0.z + v0.w*w0.w
              + v1.x*w1.x + v1.y*w1.y + v1.z*w1.z + v1.w*w1.w;
    }
  }
  #pragma unroll
  for (int j=0;j<4;++j) xout[((size_t)(b*DMC+og*4+j)<<12)+p] = acc[j];
}

// ---------- groupnorm (12 groups of 6ch) in place ----------
__global__ void k_gn(float* __restrict__ x, const float* __restrict__ g,
                     const float* __restrict__ bta){
  __shared__ float s1[256], s2[256];
  int b = blockIdx.x / GRP; int gr = blockIdx.x % GRP;
  const int CG = DMC/GRP; // 6
  float ls=0.f, lq=0.f;
  for (int i = threadIdx.x; i < CG*LL; i += 256){
    int c = gr*CG + (i>>12); int p = i & 4095;
    float v = x[((size_t)(b*DMC+c)<<12)+p];
    ls += v; lq += v*v;
  }
  s1[threadIdx.x]=ls; s2[threadIdx.x]=lq; __syncthreads();
  for (int s=128; s>0; s>>=1){
    if (threadIdx.x < s){ s1[threadIdx.x]+=s1[threadIdx.x+s]; s2[threadIdx.x]+=s2[threadIdx.x+s]; }
    __syncthreads();
  }
  float mu = s1[0]/(CG*LL);
  float var = s2[0]/(CG*LL) - mu*mu;
  float rs = rsqrtf(var + 1e-5f);
  for (int i = threadIdx.x; i < CG*LL; i += 256){
    int c = gr*CG + (i>>12); int p = i & 4095;
    size_t off = ((size_t)(b*DMC+c)<<12)+p;
    x[off] = (x[off]-mu)*rs*g[c] + bta[c];
  }
}

// ---------- dense 72x72 + bias (+ optional lrelu 0.04), 4 oc/thread ----------
__global__ void k_dense(const float* __restrict__ xin, const float* __restrict__ w,
                        const float* __restrict__ bias, float* __restrict__ xout,
                        int do_lrelu){
  int idx = blockIdx.x*256 + threadIdx.x;
  if (idx >= BB*18*LL) return;
  int p = idx & 4095; int og = (idx>>12) % 18; int b = idx / (18*LL);
  float acc[4];
  #pragma unroll
  for (int j=0;j<4;++j) acc[j] = bias[og*4+j];
  for (int c0=0; c0<DMC; c0+=8){
    float a[8];
    #pragma unroll
    for (int q=0;q<8;++q) a[q] = xin[((size_t)(b*DMC+c0+q)<<12)+p];
    #pragma unroll
    for (int j=0;j<4;++j){
      const float* wr = w + (og*4+j)*DMC + c0;
      float4 w0 = *(const float4*)(wr);
      float4 w1 = *(const float4*)(wr+4);
      acc[j] += a[0]*w0.x + a[1]*w0.y + a[2]*w0.z + a[3]*w0.w
              + a[4]*w1.x + a[5]*w1.y + a[6]*w1.z + a[7]*w1.w;
    }
  }
  #pragma unroll
  for (int j=0;j<4;++j){
    float a = acc[j];
    if (do_lrelu) a = a >= 0.f ? a : 0.04f*a;
    xout[((size_t)(b*DMC+og*4+j)<<12)+p] = a;
  }
}

// ---------- shrink conv 72->6 3x3 + sigmoid, 2 oc/thread ----------
__global__ void k_shrink(const float* __restrict__ x, const float* __restrict__ w,
                         const float* __restrict__ bias, float* __restrict__ out){
  int idx = blockIdx.x*256 + threadIdx.x;
  if (idx >= BB*3*LL) return;
  int p = idx & 4095; int o2 = (idx>>12) % 3; int b = idx / (3*LL);
  int h = p>>6, wx = p&63;
  float acc[2] = { bias[o2*2], bias[o2*2+1] };
  #pragma unroll 2
  for (int ic=0; ic<DMC; ++ic){
    const float* ip = x + ((size_t)(b*DMC+ic)<<12);
    float a[9]; gather9(ip, h, wx, a);
    #pragma unroll
    for (int j=0;j<2;++j){
      const float* wp = w + ((o2*2+j)*DMC+ic)*9;
      float s = 0.f;
      #pragma unroll
      for (int t=0;t<9;++t) s += a[t]*wp[t];
      acc[j] += s;
    }
  }
  #pragma unroll
  for (int j=0;j<2;++j)
    out[((size_t)(b*CI+o2*2+j)<<12)+p] = sigmoidf_(acc[j]);
}

extern "C" void kernel_launch(void* const* d_in, const int* in_sizes, int n_in,
                              void* d_out, int out_size, void* d_ws, size_t ws_size,
                              hipStream_t stream){
  const float* image = (const float*)d_in[0];
  const float* cb_w1 = (const float*)d_in[1];
  const float* cb_b1 = (const float*)d_in[2];
  const float* cb_w2 = (const float*)d_in[3];
  const float* cb_b2 = (const float*)d_in[4];
  const float* cb_ws = (const float*)d_in[5];
  const float* cb_bs = (const float*)d_in[6];
  const float* in_w  = (const float*)d_in[7];
  const float* dw_w  = (const float*)d_in[8];
  const float* dw_b  = (const float*)d_in[9];
  const float* xp_w  = (const float*)d_in[10];
  const float* dtp_w = (const float*)d_in[11];
  const float* dtp_b = (const float*)d_in[12];
  const float* A_logs= (const float*)d_in[13];
  const float* Ds    = (const float*)d_in[14];
  const float* ong   = (const float*)d_in[15];
  const float* onb   = (const float*)d_in[16];
  const float* op_w  = (const float*)d_in[17];
  const float* gn_g  = (const float*)d_in[18];
  const float* gn_b  = (const float*)d_in[19];
  const float* l1_w  = (const float*)d_in[20];
  const float* l1_b  = (const float*)d_in[21];
  const float* l2_w  = (const float*)d_in[22];
  const float* l2_b  = (const float*)d_in[23];
  const float* sh_w  = (const float*)d_in[24];
  const float* sh_b  = (const float*)d_in[25];

  const size_t SZ_X  = (size_t)BB*DMC*LL;       // 1,179,648
  const size_t SZ_C  = (size_t)BB*DIC*LL;       // 2,359,296
  const size_t SZ_XD = (size_t)BB*KD*20*LL;     // 1,310,720
  const size_t SZ_HP = (size_t)BB*KD*NCH*NS*DIC;// 2,359,296

  float* ws = (float*)d_ws;
  size_t off = 0;
  float* x    = ws + off; off += SZ_X;
  float* tmp  = ws + off; off += SZ_X;
  float* xz   = ws + off; off += SZ_C;   // lower 144 channels, [b][c][p]
  float* z_t  = ws + off; off += SZ_C;   // z, [b][p][c]
  float* xi_t = ws + off; off += SZ_C;   // [b][p][c]
  float* xdbl = ws + off; off += SZ_XD;
  float* cumA = ws + off; off += SZ_HP;
  float* hp   = ws + off; off += SZ_HP;
  float* y_t  = ws + off; off += SZ_C;   // [b][p][c]
  if (ws_size < off*sizeof(float)) return;

  dim3 blk(256);
  auto nb = [](long n){ return dim3((unsigned)((n + 255)/256)); };

  k_conv1<<<nb((long)BB*DMC*LL), blk, 0, stream>>>(image, cb_w1, cb_b1, tmp);
  k_conv2<<<nb((long)BB*18*LL), blk, 0, stream>>>(tmp, image, cb_w2, cb_b2, cb_ws, cb_bs, x);

  for (int i=0; i<NLAYER; ++i){
    const float* in_w_i  = in_w  + (size_t)i*2*DIC*DMC;
    const float* dw_w_i  = dw_w  + (size_t)i*DIC*9;
    const float* dw_b_i  = dw_b  + (size_t)i*DIC;
    const float* xp_w_i  = xp_w  + (size_t)i*KD*20*DIC;
    const float* dtp_w_i = dtp_w + (size_t)i*KD*DIC*RD;
    const float* dtp_b_i = dtp_b + (size_t)i*KD*DIC;
    const float* alog_i  = A_logs+ (size_t)i*KD*DIC*NS;
    const float* Ds_i    = Ds    + (size_t)i*KD*DIC;
    const float* ong_i   = ong   + (size_t)i*DIC;
    const float* onb_i   = onb   + (size_t)i*DIC;
    const float* op_w_i  = op_w  + (size_t)i*DMC*DIC;
    const float* gn_g_i  = gn_g  + (size_t)i*DMC;
    const float* gn_b_i  = gn_b  + (size_t)i*DMC;
    const float* l1_w_i  = l1_w  + (size_t)i*DMC*DMC;
    const float* l1_b_i  = l1_b  + (size_t)i*DMC;
    const float* l2_w_i  = l2_w  + (size_t)i*DMC*DMC;
    const float* l2_b_i  = l2_b  + (size_t)i*DMC;

    k_xz  <<<nb((long)BB*DMC*LL), blk, 0, stream>>>(x, in_w_i, xz, z_t);
    k_dw  <<<nb((long)BB*DIC*LL), blk, 0, stream>>>(xz, dw_w_i, dw_b_i, xi_t);
    k_xdbl<<<nb((long)BB*LL*4),  blk, 0, stream>>>(xi_t, xp_w_i, xdbl);
    k_p1  <<<nb((long)BB*KD*NCH*DIC), blk, 0, stream>>>(xi_t, xdbl, dtp_w_i, dtp_b_i, alog_i, cumA, hp);
    k_p2  <<<nb((long)BB*KD*NS*DIC), blk, 0, stream>>>(cumA, hp);
    hipMemsetAsync(y_t, 0, SZ_C*sizeof(float), stream);
    k_p3  <<<nb((long)BB*KD*NCH*DIC), blk, 0, stream>>>(xi_t, xdbl, dtp_w_i, dtp_b_i, alog_i, Ds_i, hp, y_t);
    k_lnz <<<nb((long)BB*LL*64), blk, 0, stream>>>(y_t, z_t, ong_i, onb_i);
    k_oproj<<<nb((long)BB*LL*18), blk, 0, stream>>>(y_t, op_w_i, x);
    k_gn  <<<dim3(BB*GRP), blk, 0, stream>>>(x, gn_g_i, gn_b_i);
    k_dense<<<nb((long)BB*18*LL), blk, 0, stream>>>(x, l1_w_i, l1_b_i, tmp, 1);
    k_dense<<<nb((long)BB*18*LL), blk, 0, stream>>>(tmp, l2_w_i, l2_b_i, x, 0);
  }

  k_shrink<<<nb((long)BB*3*LL), blk, 0, stream>>>(x, sh_w, sh_b, (float*)d_out);
}

// Round 4
// 651.593 us; speedup vs baseline: 3.0766x; 1.5772x over previous
//
#include <hip/hip_runtime.h>
#include <math.h>

#define BB 4
#define CI 6
#define LL 4096
#define DMC 72
#define DIC 144
#define KD 4
#define NS 8
#define RD 4
#define NLAYER 2
#define GRP 12
#define NCH 128   // chunks per scan
#define TS 32     // steps per chunk
#define PP 4356   // padded 66x66 plane

__device__ __forceinline__ float sigmoidf_(float x){ return 1.f/(1.f+__expf(-x)); }
__device__ __forceinline__ float siluf_(float x){ return x*sigmoidf_(x); }
__device__ __forceinline__ float softplusf_(float x){ return fmaxf(x,0.f) + log1pf(__expf(-fabsf(x))); }

__device__ __forceinline__ int padidx(int p){ return 66*(p>>6) + (p&63) + 67; }

// spatial position p (row-major h*64+w) for scan index l of direction k
__device__ __forceinline__ int dirmap(int k, int l){
  switch(k & 3){
    case 0: return l;
    case 1: return ((l & 63) << 6) | (l >> 6);
    case 2: return (LL-1) - l;
    default: { int m = (LL-1) - l; return ((m & 63) << 6) | (m >> 6); }
  }
}

#define LOAD9(ip, a) do { \
  a[0]=(ip)[-67]; a[1]=(ip)[-66]; a[2]=(ip)[-65]; \
  a[3]=(ip)[-1];  a[4]=(ip)[0];   a[5]=(ip)[1];   \
  a[6]=(ip)[65];  a[7]=(ip)[66];  a[8]=(ip)[67];  } while(0)

// ---------- pad copy of the input image ----------
__global__ void k_pad_img(const float* __restrict__ img, float* __restrict__ img_pad){
  int idx = blockIdx.x*256 + threadIdx.x;
  if (idx >= BB*CI*LL) return;
  int p = idx & 4095; int bc = idx >> 12;
  img_pad[(size_t)bc*PP + padidx(p)] = img[idx];
}

// ---------- conv 6->72 3x3 + lrelu(0.01); padded in, padded out ----------
__global__ void k_conv1(const float* __restrict__ img_pad, const float* __restrict__ w,
                        const float* __restrict__ bias, float* __restrict__ tmp_pad){
  int bid = blockIdx.x;
  int t = bid & 15; int r = bid >> 4; int o = r % DMC; int b = r / DMC;
  int p = t*256 + threadIdx.x;
  int pb = padidx(p);
  float acc = bias[o];
  const float* wb = w + o*CI*9;
  #pragma unroll
  for (int ic=0; ic<CI; ++ic){
    const float* ip = img_pad + (size_t)(b*CI+ic)*PP + pb;
    float a[9]; LOAD9(ip, a);
    #pragma unroll
    for (int q=0;q<9;++q) acc += a[q]*wb[ic*9+q];
  }
  tmp_pad[(size_t)(b*DMC+o)*PP + pb] = acc >= 0.f ? acc : 0.01f*acc;
}

// ---------- conv 72->72 3x3 + 1x1 shortcut + lrelu(0.01), 4 oc/thread ----------
__global__ void k_conv2(const float* __restrict__ tmp_pad, const float* __restrict__ img,
                        const float* __restrict__ w2, const float* __restrict__ b2,
                        const float* __restrict__ wsc, const float* __restrict__ bsc,
                        float* __restrict__ xout){
  int bid = blockIdx.x;
  int t = bid & 15; int r = bid >> 4; int og = r % 18; int b = r / 18;
  int p = t*256 + threadIdx.x;
  int pb = padidx(p);
  float acc[4];
  #pragma unroll
  for (int j=0;j<4;++j) acc[j] = b2[og*4+j] + bsc[og*4+j];
  const float* ipb = tmp_pad + (size_t)b*DMC*PP + pb;
  const float* wb  = w2 + (size_t)(og*4)*DMC*9;
  #pragma unroll 2
  for (int ic=0; ic<DMC; ++ic){
    const float* ip = ipb + (size_t)ic*PP;
    float a[9]; LOAD9(ip, a);
    const float* wp = wb + ic*9;
    #pragma unroll
    for (int j=0;j<4;++j){
      float s = 0.f;
      #pragma unroll
      for (int q=0;q<9;++q) s += a[q]*wp[(size_t)j*DMC*9 + q];
      acc[j] += s;
    }
  }
  #pragma unroll
  for (int ic=0; ic<CI; ++ic){
    float v = img[((b*CI+ic)<<12)+p];
    #pragma unroll
    for (int j=0;j<4;++j) acc[j] += v * wsc[(og*4+j)*CI+ic];
  }
  #pragma unroll
  for (int j=0;j<4;++j){
    float a = acc[j];
    xout[((b*DMC+og*4+j)<<12)+p] = a >= 0.f ? a : 0.01f*a;
  }
}

// ---------- xz: first 144 ch -> padded planes (for dw); last 144 (z) -> z_t [b][p][c] ----------
__global__ void k_xz(const float* __restrict__ x, const float* __restrict__ inw,
                     float* __restrict__ xz_pad, float* __restrict__ z_t){
  int bid = blockIdx.x;
  int t = bid & 15; int r = bid >> 4; int eg = r % DMC; int b = r / DMC;
  int p = t*256 + threadIdx.x;
  float acc[4] = {0.f,0.f,0.f,0.f};
  for (int c0=0; c0<DMC; c0+=8){
    float a[8];
    #pragma unroll
    for (int q=0;q<8;++q) a[q] = x[((b*DMC+c0+q)<<12)+p];
    #pragma unroll
    for (int j=0;j<4;++j){
      const float* w = inw + (eg*4+j)*DMC + c0;
      float4 w0 = *(const float4*)(w);
      float4 w1 = *(const float4*)(w+4);
      acc[j] += a[0]*w0.x + a[1]*w0.y + a[2]*w0.z + a[3]*w0.w
              + a[4]*w1.x + a[5]*w1.y + a[6]*w1.z + a[7]*w1.w;
    }
  }
  if (eg < 36){
    int pb = padidx(p);
    #pragma unroll
    for (int j=0;j<4;++j) xz_pad[(size_t)(b*DIC+eg*4+j)*PP + pb] = acc[j];
  } else {
    float4 v4 = make_float4(acc[0],acc[1],acc[2],acc[3]);
    *(float4*)(z_t + ((size_t)b*LL+p)*DIC + (eg*4-DIC)) = v4;
  }
}

// ---------- depthwise 3x3 + bias + silu -> xi_t [b][p][c] ----------
__global__ void k_dw(const float* __restrict__ xz_pad, const float* __restrict__ dww,
                     const float* __restrict__ dwb, float* __restrict__ xi_t){
  int bid = blockIdx.x;
  int t = bid & 15; int r = bid >> 4; int c = r % DIC; int b = r / DIC;
  int p = t*256 + threadIdx.x;
  int pb = padidx(p);
  const float* ip = xz_pad + (size_t)(b*DIC+c)*PP + pb;
  const float* wp = dww + c*9;
  float a[9]; LOAD9(ip, a);
  float acc = dwb[c];
  #pragma unroll
  for (int q=0;q<9;++q) acc += a[q]*wp[q];
  xi_t[((size_t)b*LL+p)*DIC + c] = siluf_(acc);
}

// ---------- x_dbl stored at SPATIAL index p for all 4 dirs; thread=(b,part,k,ptile) ----------
__global__ void k_xdbl(const float* __restrict__ xi_t, const float* __restrict__ xpw,
                       float* __restrict__ xdbl){
  int bid = blockIdx.x;
  int t = bid & 15; int r = bid >> 4;
  int kk = r & 3; r >>= 2; int part = r & 3; int b = r >> 2;
  int p = t*256 + threadIdx.x;
  const float* xib = xi_t + ((size_t)b*LL + p)*DIC;
  const float* wk = xpw + (size_t)(kk*20 + part*5)*DIC;
  float acc[5] = {0.f,0.f,0.f,0.f,0.f};
  for (int d=0; d<DIC; d+=4){
    float4 v = *(const float4*)(xib + d);
    #pragma unroll
    for (int c=0;c<5;++c){
      float4 w = *(const float4*)(wk + (size_t)c*DIC + d);
      acc[c] += v.x*w.x + v.y*w.y + v.z*w.z + v.w*w.w;
    }
  }
  #pragma unroll
  for (int c=0;c<5;++c)
    xdbl[((size_t)(b*KD+kk)*20 + part*5 + c)*LL + p] = acc[c];
}

__device__ __forceinline__ void scan_decode(int idx, int& b, int& k, int& ch, int& c){
  c = idx % DIC;
  int r = idx / DIC;
  ch = r % NCH;
  r /= NCH;
  k = r & 3; b = r >> 2;
}

// ---------- P1: per-chunk summaries (cumA, partial state), layout [bk][ch][n][c] ----------
__global__ void k_p1(const float* __restrict__ xi_t, const float* __restrict__ xdbl,
                     const float* __restrict__ dtpw, const float* __restrict__ dtpb,
                     const float* __restrict__ alog,
                     float* __restrict__ cumA, float* __restrict__ hp){
  int idx = blockIdx.x*256 + threadIdx.x;
  if (idx >= BB*KD*NCH*DIC) return;
  int b,k,ch,c; scan_decode(idx,b,k,ch,c);
  float Arow[NS];
  #pragma unroll
  for (int n=0;n<NS;++n) Arow[n] = -__expf(alog[(k*DIC+c)*NS+n]);
  float wdt[RD];
  #pragma unroll
  for (int r=0;r<RD;++r) wdt[r] = dtpw[(k*DIC+c)*RD+r];
  float bdt = dtpb[k*DIC+c];
  const float* xd = xdbl + (size_t)(b*KD+k)*20*LL;
  const float* xib = xi_t + (size_t)b*LL*DIC + c;
  float h[NS];
  #pragma unroll
  for (int n=0;n<NS;++n) h[n]=0.f;
  float sumd = 0.f;
  #pragma unroll 4
  for (int t=0; t<TS; ++t){
    int l = ch*TS + t;
    int ps = dirmap(k,l);
    float din[RD];
    #pragma unroll
    for (int r=0;r<RD;++r) din[r] = xd[r*LL + ps];
    float Bv[NS];
    #pragma unroll
    for (int n=0;n<NS;++n) Bv[n] = xd[(RD+n)*LL + ps];
    float u = xib[(size_t)ps*DIC];
    float dt = bdt;
    #pragma unroll
    for (int r=0;r<RD;++r) dt += din[r]*wdt[r];
    dt = softplusf_(dt);
    sumd += dt;
    float du = dt*u;
    #pragma unroll
    for (int n=0;n<NS;++n)
      h[n] = h[n]*__expf(dt*Arow[n]) + du*Bv[n];
  }
  size_t base = ((size_t)((b*KD+k)*NCH + ch)*NS)*DIC + c;
  #pragma unroll
  for (int n=0;n<NS;++n) hp[base + n*DIC] = h[n];
  #pragma unroll
  for (int n=0;n<NS;++n) cumA[base + n*DIC] = __expf(sumd*Arow[n]);
}

// ---------- P2: prefix over chunk summaries, thread per (bk,n,c); hp becomes h_in ----------
__global__ void k_p2(const float* __restrict__ cumA, float* __restrict__ hp){
  int idx = blockIdx.x*256 + threadIdx.x;
  if (idx >= BB*KD*NS*DIC) return;
  int c = idx % DIC; int n = (idx/DIC) % NS; int bk = idx/(DIC*NS);
  float h = 0.f;
  #pragma unroll 4
  for (int ch=0; ch<NCH; ++ch){
    size_t base = ((size_t)(bk*NCH+ch)*NS + n)*DIC + c;
    float a = cumA[base];
    float pp = hp[base];
    hp[base] = h;
    h = a*h + pp;
  }
}

// ---------- P3: replay chunks, accumulate into y_t [b][p][c] with coalesced atomics ----------
__global__ void k_p3(const float* __restrict__ xi_t, const float* __restrict__ xdbl,
                     const float* __restrict__ dtpw, const float* __restrict__ dtpb,
                     const float* __restrict__ alog, const float* __restrict__ Dsv,
                     const float* __restrict__ hin, float* __restrict__ y_t){
  int idx = blockIdx.x*256 + threadIdx.x;
  if (idx >= BB*KD*NCH*DIC) return;
  int b,k,ch,c; scan_decode(idx,b,k,ch,c);
  float Arow[NS];
  #pragma unroll
  for (int n=0;n<NS;++n) Arow[n] = -__expf(alog[(k*DIC+c)*NS+n]);
  float wdt[RD];
  #pragma unroll
  for (int r=0;r<RD;++r) wdt[r] = dtpw[(k*DIC+c)*RD+r];
  float bdt = dtpb[k*DIC+c];
  float Dv = Dsv[k*DIC+c];
  const float* xd = xdbl + (size_t)(b*KD+k)*20*LL;
  const float* xib = xi_t + (size_t)b*LL*DIC + c;
  float* yb = y_t + (size_t)b*LL*DIC + c;
  float h[NS];
  size_t base = ((size_t)((b*KD+k)*NCH + ch)*NS)*DIC + c;
  #pragma unroll
  for (int n=0;n<NS;++n) h[n] = hin[base + n*DIC];
  #pragma unroll 4
  for (int t=0; t<TS; ++t){
    int l = ch*TS + t;
    int ps = dirmap(k,l);
    float din[RD];
    #pragma unroll
    for (int r=0;r<RD;++r) din[r] = xd[r*LL + ps];
    float Bv[NS], Cv[NS];
    #pragma unroll
    for (int n=0;n<NS;++n) Bv[n] = xd[(RD+n)*LL + ps];
    #pragma unroll
    for (int n=0;n<NS;++n) Cv[n] = xd[(RD+NS+n)*LL + ps];
    float u = xib[(size_t)ps*DIC];
    float dt = bdt;
    #pragma unroll
    for (int r=0;r<RD;++r) dt += din[r]*wdt[r];
    dt = softplusf_(dt);
    float du = dt*u;
    float y = 0.f;
    #pragma unroll
    for (int n=0;n<NS;++n){
      h[n] = h[n]*__expf(dt*Arow[n]) + du*Bv[n];
      y += h[n]*Cv[n];
    }
    y += u*Dv;
    atomicAdd(yb + (size_t)ps*DIC, y);
  }
}

// ---------- LN over c per pixel (wave-per-pixel), * ong+onb, * silu(z); in place ----------
__global__ void k_lnz(float* __restrict__ y_t, const float* __restrict__ z_t,
                      const float* __restrict__ ong, const float* __restrict__ onb){
  int gid = blockIdx.x*256 + threadIdx.x;
  int wid = gid >> 6;
  int lane = gid & 63;
  if (wid >= BB*LL) return;
  size_t rb = (size_t)wid * DIC;
  float v0 = y_t[rb + lane];
  float v1 = y_t[rb + 64 + lane];
  float v2 = (lane < 16) ? y_t[rb + 128 + lane] : 0.f;
  float s = v0 + v1 + v2;
  float q = v0*v0 + v1*v1 + v2*v2;
  #pragma unroll
  for (int o=32; o>0; o>>=1){ s += __shfl_xor(s,o,64); q += __shfl_xor(q,o,64); }
  float mu = s*(1.f/DIC);
  float var = q*(1.f/DIC) - mu*mu;
  float rs = rsqrtf(var + 1e-5f);
  float z0 = z_t[rb + lane];
  y_t[rb + lane] = ((v0-mu)*rs*ong[lane] + onb[lane]) * siluf_(z0);
  float z1 = z_t[rb + 64 + lane];
  y_t[rb + 64 + lane] = ((v1-mu)*rs*ong[64+lane] + onb[64+lane]) * siluf_(z1);
  if (lane < 16){
    float z2 = z_t[rb + 128 + lane];
    y_t[rb + 128 + lane] = ((v2-mu)*rs*ong[128+lane] + onb[128+lane]) * siluf_(z2);
  }
}

// ---------- out-proj: LDS-staged y tile (transposed, stride 65), 18 oc per thread ----------
__global__ void k_oproj(const float* __restrict__ y_t, const float* __restrict__ opw,
                        float* __restrict__ xout){
  __shared__ float ly[DIC*65];
  int bid = blockIdx.x;              // BB * 64 tiles
  int tile = bid & 63; int b = bid >> 6;
  int pstart = tile*64;
  const float* src = y_t + ((size_t)b*LL + pstart)*DIC;
  for (int i = threadIdx.x; i < 64*DIC; i += 256){
    int px = i / DIC; int d = i - px*DIC;
    ly[d*65 + px] = src[i];
  }
  __syncthreads();
  int px = threadIdx.x & 63;
  int ocg = __builtin_amdgcn_readfirstlane(threadIdx.x >> 6);  // 0..3 wave-uniform
  float acc[18];
  #pragma unroll
  for (int j=0;j<18;++j) acc[j]=0.f;
  const float* wb = opw + (size_t)ocg*18*DIC;
  #pragma unroll 4
  for (int d=0; d<DIC; ++d){
    float a = ly[d*65 + px];
    #pragma unroll
    for (int j=0;j<18;++j) acc[j] += a * wb[(size_t)j*DIC + d];
  }
  #pragma unroll
  for (int j=0;j<18;++j)
    xout[((size_t)(b*DMC + ocg*18 + j)<<12) + pstart + px] = acc[j];
}

// ---------- groupnorm (12 groups of 6ch) in place ----------
__global__ void k_gn(float* __restrict__ x, const float* __restrict__ g,
                     const float* __restrict__ bta){
  __shared__ float s1[256], s2[256];
  int b = blockIdx.x / GRP; int gr = blockIdx.x % GRP;
  const int CG = DMC/GRP; // 6
  float ls=0.f, lq=0.f;
  for (int i = threadIdx.x; i < CG*LL; i += 256){
    int c = gr*CG + (i>>12); int p = i & 4095;
    float v = x[((size_t)(b*DMC+c)<<12)+p];
    ls += v; lq += v*v;
  }
  s1[threadIdx.x]=ls; s2[threadIdx.x]=lq; __syncthreads();
  for (int s=128; s>0; s>>=1){
    if (threadIdx.x < s){ s1[threadIdx.x]+=s1[threadIdx.x+s]; s2[threadIdx.x]+=s2[threadIdx.x+s]; }
    __syncthreads();
  }
  float mu = s1[0]/(CG*LL);
  float var = s2[0]/(CG*LL) - mu*mu;
  float rs = rsqrtf(var + 1e-5f);
  for (int i = threadIdx.x; i < CG*LL; i += 256){
    int c = gr*CG + (i>>12); int p = i & 4095;
    size_t off = ((size_t)(b*DMC+c)<<12)+p;
    x[off] = (x[off]-mu)*rs*g[c] + bta[c];
  }
}

// ---------- dense 72x72 + bias (+ optional lrelu 0.04), 4 oc/thread ----------
__global__ void k_dense(const float* __restrict__ xin, const float* __restrict__ w,
                        const float* __restrict__ bias, float* __restrict__ xout,
                        float* __restrict__ pad_out, int do_lrelu){
  int bid = blockIdx.x;
  int t = bid & 15; int r = bid >> 4; int eg = r % 18; int b = r / 18;
  int p = t*256 + threadIdx.x;
  float acc[4];
  #pragma unroll
  for (int j=0;j<4;++j) acc[j] = bias[eg*4+j];
  for (int c0=0; c0<DMC; c0+=8){
    float a[8];
    #pragma unroll
    for (int q=0;q<8;++q) a[q] = xin[((size_t)(b*DMC+c0+q)<<12)+p];
    #pragma unroll
    for (int j=0;j<4;++j){
      const float* wr = w + (eg*4+j)*DMC + c0;
      float4 w0 = *(const float4*)(wr);
      float4 w1 = *(const float4*)(wr+4);
      acc[j] += a[0]*w0.x + a[1]*w0.y + a[2]*w0.z + a[3]*w0.w
              + a[4]*w1.x + a[5]*w1.y + a[6]*w1.z + a[7]*w1.w;
    }
  }
  int pb = padidx(p);
  #pragma unroll
  for (int j=0;j<4;++j){
    float a = acc[j];
    if (do_lrelu) a = a >= 0.f ? a : 0.04f*a;
    xout[((size_t)(b*DMC+eg*4+j)<<12)+p] = a;
    if (pad_out) pad_out[(size_t)(b*DMC+eg*4+j)*PP + pb] = a;
  }
}

// ---------- shrink conv 72->6 3x3 + sigmoid, 2 oc/thread, padded input ----------
__global__ void k_shrink(const float* __restrict__ x_pad, const float* __restrict__ w,
                         const float* __restrict__ bias, float* __restrict__ out){
  int bid = blockIdx.x;
  int t = bid & 15; int r = bid >> 4; int o2 = r % 3; int b = r / 3;
  int p = t*256 + threadIdx.x;
  int pb = padidx(p);
  float acc[2] = { bias[o2*2], bias[o2*2+1] };
  const float* ipb = x_pad + (size_t)b*DMC*PP + pb;
  #pragma unroll 2
  for (int ic=0; ic<DMC; ++ic){
    const float* ip = ipb + (size_t)ic*PP;
    float a[9]; LOAD9(ip, a);
    #pragma unroll
    for (int j=0;j<2;++j){
      const float* wp = w + ((o2*2+j)*DMC+ic)*9;
      float s = 0.f;
      #pragma unroll
      for (int q=0;q<9;++q) s += a[q]*wp[q];
      acc[j] += s;
    }
  }
  #pragma unroll
  for (int j=0;j<2;++j)
    out[((size_t)(b*CI+o2*2+j)<<12)+p] = sigmoidf_(acc[j]);
}

extern "C" void kernel_launch(void* const* d_in, const int* in_sizes, int n_in,
                              void* d_out, int out_size, void* d_ws, size_t ws_size,
                              hipStream_t stream){
  const float* image = (const float*)d_in[0];
  const float* cb_w1 = (const float*)d_in[1];
  const float* cb_b1 = (const float*)d_in[2];
  const float* cb_w2 = (const float*)d_in[3];
  const float* cb_b2 = (const float*)d_in[4];
  const float* cb_ws = (const float*)d_in[5];
  const float* cb_bs = (const float*)d_in[6];
  const float* in_w  = (const float*)d_in[7];
  const float* dw_w  = (const float*)d_in[8];
  const float* dw_b  = (const float*)d_in[9];
  const float* xp_w  = (const float*)d_in[10];
  const float* dtp_w = (const float*)d_in[11];
  const float* dtp_b = (const float*)d_in[12];
  const float* A_logs= (const float*)d_in[13];
  const float* Ds    = (const float*)d_in[14];
  const float* ong   = (const float*)d_in[15];
  const float* onb   = (const float*)d_in[16];
  const float* op_w  = (const float*)d_in[17];
  const float* gn_g  = (const float*)d_in[18];
  const float* gn_b  = (const float*)d_in[19];
  const float* l1_w  = (const float*)d_in[20];
  const float* l1_b  = (const float*)d_in[21];
  const float* l2_w  = (const float*)d_in[22];
  const float* l2_b  = (const float*)d_in[23];
  const float* sh_w  = (const float*)d_in[24];
  const float* sh_b  = (const float*)d_in[25];

  const size_t SZ_X  = (size_t)BB*DMC*LL;        // 1,179,648
  const size_t SZ_C  = (size_t)BB*DIC*LL;        // 2,359,296
  const size_t SZ_XD = (size_t)BB*KD*20*LL;      // 1,310,720
  const size_t SZ_IP = (size_t)BB*CI*PP;         // img_pad
  const size_t SZ_TP = (size_t)BB*DMC*PP;        // tmp_pad (= xfin_pad)
  const size_t SZ_ZP = (size_t)BB*DIC*PP;        // xz_pad

  float* ws = (float*)d_ws;
  size_t off = 0;
  float* x     = ws + off; off += SZ_X;
  float* tmp   = ws + off; off += SZ_X;
  float* z_t   = ws + off; off += SZ_C;
  float* xi_t  = ws + off; off += SZ_C;
  float* xdbl  = ws + off; off += SZ_XD;
  float* cumA  = ws + off; off += SZ_C;   // aliased: cumA (p1/p2) then y_t (p3..oproj)
  float* hp    = ws + off; off += SZ_C;
  float* pads  = ws + off;
  float* img_pad = pads;
  float* tmp_pad = img_pad + SZ_IP;       // also xfin_pad for shrink
  float* xz_pad  = tmp_pad + SZ_TP;
  off += SZ_IP + SZ_TP + SZ_ZP;
  if (ws_size < off*sizeof(float)) return;
  float* y_t = cumA;

  dim3 blk(256);

  // zero padded buffers (halos must be 0; interiors are overwritten each call)
  hipMemsetAsync(pads, 0, (SZ_IP+SZ_TP+SZ_ZP)*sizeof(float), stream);

  k_pad_img<<<dim3(BB*CI*16), blk, 0, stream>>>(image, img_pad);
  k_conv1<<<dim3(BB*DMC*16), blk, 0, stream>>>(img_pad, cb_w1, cb_b1, tmp_pad);
  k_conv2<<<dim3(BB*18*16), blk, 0, stream>>>(tmp_pad, image, cb_w2, cb_b2, cb_ws, cb_bs, x);

  for (int i=0; i<NLAYER; ++i){
    const float* in_w_i  = in_w  + (size_t)i*2*DIC*DMC;
    const float* dw_w_i  = dw_w  + (size_t)i*DIC*9;
    const float* dw_b_i  = dw_b  + (size_t)i*DIC;
    const float* xp_w_i  = xp_w  + (size_t)i*KD*20*DIC;
    const float* dtp_w_i = dtp_w + (size_t)i*KD*DIC*RD;
    const float* dtp_b_i = dtp_b + (size_t)i*KD*DIC;
    const float* alog_i  = A_logs+ (size_t)i*KD*DIC*NS;
    const float* Ds_i    = Ds    + (size_t)i*KD*DIC;
    const float* ong_i   = ong   + (size_t)i*DIC;
    const float* onb_i   = onb   + (size_t)i*DIC;
    const float* op_w_i  = op_w  + (size_t)i*DMC*DIC;
    const float* gn_g_i  = gn_g  + (size_t)i*DMC;
    const float* gn_b_i  = gn_b  + (size_t)i*DMC;
    const float* l1_w_i  = l1_w  + (size_t)i*DMC*DMC;
    const float* l1_b_i  = l1_b  + (size_t)i*DMC;
    const float* l2_w_i  = l2_w  + (size_t)i*DMC*DMC;
    const float* l2_b_i  = l2_b  + (size_t)i*DMC;

    k_xz  <<<dim3(BB*DMC*16), blk, 0, stream>>>(x, in_w_i, xz_pad, z_t);
    k_dw  <<<dim3(BB*DIC*16), blk, 0, stream>>>(xz_pad, dw_w_i, dw_b_i, xi_t);
    k_xdbl<<<dim3(BB*KD*KD*16), blk, 0, stream>>>(xi_t, xp_w_i, xdbl);
    k_p1  <<<dim3(BB*KD*NCH*DIC/256), blk, 0, stream>>>(xi_t, xdbl, dtp_w_i, dtp_b_i, alog_i, cumA, hp);
    k_p2  <<<dim3(BB*KD*NS*DIC/256), blk, 0, stream>>>(cumA, hp);
    hipMemsetAsync(y_t, 0, SZ_C*sizeof(float), stream);
    k_p3  <<<dim3(BB*KD*NCH*DIC/256), blk, 0, stream>>>(xi_t, xdbl, dtp_w_i, dtp_b_i, alog_i, Ds_i, hp, y_t);
    k_lnz <<<dim3(BB*LL/4), blk, 0, stream>>>(y_t, z_t, ong_i, onb_i);
    k_oproj<<<dim3(BB*64), blk, 0, stream>>>(y_t, op_w_i, x);
    k_gn  <<<dim3(BB*GRP), blk, 0, stream>>>(x, gn_g_i, gn_b_i);
    k_dense<<<dim3(BB*18*16), blk, 0, stream>>>(x, l1_w_i, l1_b_i, tmp, (float*)nullptr, 1);
    k_dense<<<dim3(BB*18*16), blk, 0, stream>>>(tmp, l2_w_i, l2_b_i, x,
                                                (i==NLAYER-1) ? tmp_pad : (float*)nullptr, 0);
  }

  k_shrink<<<dim3(BB*3*16), blk, 0, stream>>>(tmp_pad, sh_w, sh_b, (float*)d_out);
}

// Round 5
// 576.391 us; speedup vs baseline: 3.4781x; 1.1305x over previous
//
#include <hip/hip_runtime.h>
#include <math.h>

#define BB 4
#define CI 6
#define LL 4096
#define DMC 72
#define DIC 144
#define KD 4
#define NS 8
#define RD 4
#define NLAYER 2
#define GRP 12
#define NCH 128   // chunks per scan
#define TS 32     // steps per chunk
#define PP 4356   // padded 66x66 plane

__device__ __forceinline__ float sigmoidf_(float x){ return 1.f/(1.f+__expf(-x)); }
__device__ __forceinline__ float siluf_(float x){ return x*sigmoidf_(x); }
// fast softplus: |err| << 2e-3 tolerance
__device__ __forceinline__ float softplusf_(float x){
  return fmaxf(x,0.f) + __logf(1.f + __expf(-fabsf(x)));
}

__device__ __forceinline__ int padidx(int p){ return 66*(p>>6) + (p&63) + 67; }

// spatial position p (row-major h*64+w) for scan index l of direction k
__device__ __forceinline__ int dirmap(int k, int l){
  switch(k & 3){
    case 0: return l;
    case 1: return ((l & 63) << 6) | (l >> 6);
    case 2: return (LL-1) - l;
    default: { int m = (LL-1) - l; return ((m & 63) << 6) | (m >> 6); }
  }
}

#define LOAD9(ip, a) do { \
  a[0]=(ip)[-67]; a[1]=(ip)[-66]; a[2]=(ip)[-65]; \
  a[3]=(ip)[-1];  a[4]=(ip)[0];   a[5]=(ip)[1];   \
  a[6]=(ip)[65];  a[7]=(ip)[66];  a[8]=(ip)[67];  } while(0)

// ---------- pad copy of the input image ----------
__global__ void k_pad_img(const float* __restrict__ img, float* __restrict__ img_pad){
  int idx = blockIdx.x*256 + threadIdx.x;
  if (idx >= BB*CI*LL) return;
  int p = idx & 4095; int bc = idx >> 12;
  img_pad[(size_t)bc*PP + padidx(p)] = img[idx];
}

// ---------- conv 6->72 3x3 + lrelu(0.01); padded in, padded out ----------
__global__ void k_conv1(const float* __restrict__ img_pad, const float* __restrict__ w,
                        const float* __restrict__ bias, float* __restrict__ tmp_pad){
  int bid = blockIdx.x;
  int t = bid & 15; int r = bid >> 4; int o = r % DMC; int b = r / DMC;
  int p = t*256 + threadIdx.x;
  int pb = padidx(p);
  float acc = bias[o];
  const float* wb = w + o*CI*9;
  #pragma unroll
  for (int ic=0; ic<CI; ++ic){
    const float* ip = img_pad + (size_t)(b*CI+ic)*PP + pb;
    float a[9]; LOAD9(ip, a);
    #pragma unroll
    for (int q=0;q<9;++q) acc += a[q]*wb[ic*9+q];
  }
  tmp_pad[(size_t)(b*DMC+o)*PP + pb] = acc >= 0.f ? acc : 0.01f*acc;
}

// ---------- conv 72->72 3x3 + 1x1 shortcut + lrelu(0.01), 8 oc/thread ----------
__global__ void k_conv2(const float* __restrict__ tmp_pad, const float* __restrict__ img,
                        const float* __restrict__ w2, const float* __restrict__ b2,
                        const float* __restrict__ wsc, const float* __restrict__ bsc,
                        float* __restrict__ xout){
  int bid = blockIdx.x;
  int t = bid & 15; int r = bid >> 4; int og = r % 9; int b = r / 9;
  int p = t*256 + threadIdx.x;
  int pb = padidx(p);
  float acc[8];
  #pragma unroll
  for (int j=0;j<8;++j) acc[j] = b2[og*8+j] + bsc[og*8+j];
  const float* ipb = tmp_pad + (size_t)b*DMC*PP + pb;
  const float* wb  = w2 + (size_t)(og*8)*DMC*9;
  #pragma unroll 2
  for (int ic=0; ic<DMC; ++ic){
    const float* ip = ipb + (size_t)ic*PP;
    float a[9]; LOAD9(ip, a);
    const float* wp = wb + ic*9;
    #pragma unroll
    for (int j=0;j<8;++j){
      float s = 0.f;
      #pragma unroll
      for (int q=0;q<9;++q) s += a[q]*wp[(size_t)j*DMC*9 + q];
      acc[j] += s;
    }
  }
  #pragma unroll
  for (int ic=0; ic<CI; ++ic){
    float v = img[((b*CI+ic)<<12)+p];
    #pragma unroll
    for (int j=0;j<8;++j) acc[j] += v * wsc[(og*8+j)*CI+ic];
  }
  #pragma unroll
  for (int j=0;j<8;++j){
    float a = acc[j];
    xout[((b*DMC+og*8+j)<<12)+p] = a >= 0.f ? a : 0.01f*a;
  }
}

// ---------- xz: first 144 ch -> padded planes (for dw); last 144 (z) -> z_t [b][p][c] ----------
__global__ void k_xz(const float* __restrict__ x, const float* __restrict__ inw,
                     float* __restrict__ xz_pad, float* __restrict__ z_t){
  int bid = blockIdx.x;
  int t = bid & 15; int r = bid >> 4; int eg = r % 36; int b = r / 36;
  int p = t*256 + threadIdx.x;
  float acc[8] = {0.f,0.f,0.f,0.f,0.f,0.f,0.f,0.f};
  for (int c0=0; c0<DMC; c0+=4){
    float a[4];
    #pragma unroll
    for (int q=0;q<4;++q) a[q] = x[((b*DMC+c0+q)<<12)+p];
    #pragma unroll
    for (int j=0;j<8;++j){
      float4 w = *(const float4*)(inw + (eg*8+j)*DMC + c0);
      acc[j] += a[0]*w.x + a[1]*w.y + a[2]*w.z + a[3]*w.w;
    }
  }
  if (eg < 18){
    int pb = padidx(p);
    #pragma unroll
    for (int j=0;j<8;++j) xz_pad[(size_t)(b*DIC+eg*8+j)*PP + pb] = acc[j];
  } else {
    float* zb = z_t + ((size_t)b*LL+p)*DIC + (eg*8-DIC);
    *(float4*)(zb)   = make_float4(acc[0],acc[1],acc[2],acc[3]);
    *(float4*)(zb+4) = make_float4(acc[4],acc[5],acc[6],acc[7]);
  }
}

// ---------- depthwise 3x3 + bias + silu -> xi_t [b][p][c] ----------
__global__ void k_dw(const float* __restrict__ xz_pad, const float* __restrict__ dww,
                     const float* __restrict__ dwb, float* __restrict__ xi_t){
  int bid = blockIdx.x;
  int t = bid & 15; int r = bid >> 4; int c = r % DIC; int b = r / DIC;
  int p = t*256 + threadIdx.x;
  int pb = padidx(p);
  const float* ip = xz_pad + (size_t)(b*DIC+c)*PP + pb;
  const float* wp = dww + c*9;
  float a[9]; LOAD9(ip, a);
  float acc = dwb[c];
  #pragma unroll
  for (int q=0;q<9;++q) acc += a[q]*wp[q];
  xi_t[((size_t)b*LL+p)*DIC + c] = siluf_(acc);
}

// ---------- x_dbl stored as [bk][l(spatial p)][20]; thread=(b,part,k,ptile) ----------
__global__ void k_xdbl(const float* __restrict__ xi_t, const float* __restrict__ xpw,
                       float* __restrict__ xdbl){
  int bid = blockIdx.x;
  int t = bid & 15; int r = bid >> 4;
  int kk = r & 3; r >>= 2; int part = r & 3; int b = r >> 2;
  int p = t*256 + threadIdx.x;
  const float* xib = xi_t + ((size_t)b*LL + p)*DIC;
  const float* wk = xpw + (size_t)(kk*20 + part*5)*DIC;
  float acc[5] = {0.f,0.f,0.f,0.f,0.f};
  for (int d=0; d<DIC; d+=4){
    float4 v = *(const float4*)(xib + d);
    #pragma unroll
    for (int c=0;c<5;++c){
      float4 w = *(const float4*)(wk + (size_t)c*DIC + d);
      acc[c] += v.x*w.x + v.y*w.y + v.z*w.z + v.w*w.w;
    }
  }
  float* dst = xdbl + ((size_t)(b*KD+kk)*LL + p)*20 + part*5;
  #pragma unroll
  for (int c=0;c<5;++c) dst[c] = acc[c];
}

__device__ __forceinline__ void scan_decode(int idx, int& b, int& k, int& ch, int& c){
  c = idx % DIC;
  int r = idx / DIC;
  ch = r % NCH;
  r /= NCH;
  k = r & 3; b = r >> 2;
}

// ---------- P1: per-chunk summaries (cumA, partial state), layout [bk][ch][n][c] ----------
__global__ void k_p1(const float* __restrict__ xi_t, const float* __restrict__ xdbl,
                     const float* __restrict__ dtpw, const float* __restrict__ dtpb,
                     const float* __restrict__ alog,
                     float* __restrict__ cumA, float* __restrict__ hp){
  int idx = blockIdx.x*256 + threadIdx.x;
  if (idx >= BB*KD*NCH*DIC) return;
  int b,k,ch,c; scan_decode(idx,b,k,ch,c);
  float Arow[NS];
  #pragma unroll
  for (int n=0;n<NS;++n) Arow[n] = -__expf(alog[(k*DIC+c)*NS+n]);
  float4 wdt = *(const float4*)(dtpw + (k*DIC+c)*RD);
  float bdt = dtpb[k*DIC+c];
  const float* xd = xdbl + (size_t)(b*KD+k)*LL*20;
  const float* xib = xi_t + (size_t)b*LL*DIC + c;
  float h[NS];
  #pragma unroll
  for (int n=0;n<NS;++n) h[n]=0.f;
  float sumd = 0.f;
  #pragma unroll 2
  for (int t=0; t<TS; ++t){
    int l = ch*TS + t;
    int ps = dirmap(k,l);
    const float* row = xd + (size_t)ps*20;
    float4 q0 = *(const float4*)(row);
    float4 q1 = *(const float4*)(row+4);
    float4 q2 = *(const float4*)(row+8);
    float u = xib[(size_t)ps*DIC];
    float dt = bdt + q0.x*wdt.x + q0.y*wdt.y + q0.z*wdt.z + q0.w*wdt.w;
    dt = softplusf_(dt);
    sumd += dt;
    float du = dt*u;
    float Bv[NS] = {q1.x,q1.y,q1.z,q1.w,q2.x,q2.y,q2.z,q2.w};
    #pragma unroll
    for (int n=0;n<NS;++n)
      h[n] = h[n]*__expf(dt*Arow[n]) + du*Bv[n];
  }
  size_t base = ((size_t)((b*KD+k)*NCH + ch)*NS)*DIC + c;
  #pragma unroll
  for (int n=0;n<NS;++n) hp[base + n*DIC] = h[n];
  #pragma unroll
  for (int n=0;n<NS;++n) cumA[base + n*DIC] = __expf(sumd*Arow[n]);
}

// ---------- P2: prefix over chunk summaries, thread per (bk,n,c); hp becomes h_in ----------
__global__ void k_p2(const float* __restrict__ cumA, float* __restrict__ hp){
  int idx = blockIdx.x*256 + threadIdx.x;
  if (idx >= BB*KD*NS*DIC) return;
  int c = idx % DIC; int n = (idx/DIC) % NS; int bk = idx/(DIC*NS);
  float h = 0.f;
  #pragma unroll 4
  for (int ch=0; ch<NCH; ++ch){
    size_t base = ((size_t)(bk*NCH+ch)*NS + n)*DIC + c;
    float a = cumA[base];
    float pp = hp[base];
    hp[base] = h;
    h = a*h + pp;
  }
}

// ---------- P3: replay chunks, accumulate into y_t [b][p][c] with coalesced atomics ----------
__global__ void k_p3(const float* __restrict__ xi_t, const float* __restrict__ xdbl,
                     const float* __restrict__ dtpw, const float* __restrict__ dtpb,
                     const float* __restrict__ alog, const float* __restrict__ Dsv,
                     const float* __restrict__ hin, float* __restrict__ y_t){
  int idx = blockIdx.x*256 + threadIdx.x;
  if (idx >= BB*KD*NCH*DIC) return;
  int b,k,ch,c; scan_decode(idx,b,k,ch,c);
  float Arow[NS];
  #pragma unroll
  for (int n=0;n<NS;++n) Arow[n] = -__expf(alog[(k*DIC+c)*NS+n]);
  float4 wdt = *(const float4*)(dtpw + (k*DIC+c)*RD);
  float bdt = dtpb[k*DIC+c];
  float Dv = Dsv[k*DIC+c];
  const float* xd = xdbl + (size_t)(b*KD+k)*LL*20;
  const float* xib = xi_t + (size_t)b*LL*DIC + c;
  float* yb = y_t + (size_t)b*LL*DIC + c;
  float h[NS];
  size_t base = ((size_t)((b*KD+k)*NCH + ch)*NS)*DIC + c;
  #pragma unroll
  for (int n=0;n<NS;++n) h[n] = hin[base + n*DIC];
  #pragma unroll 2
  for (int t=0; t<TS; ++t){
    int l = ch*TS + t;
    int ps = dirmap(k,l);
    const float* row = xd + (size_t)ps*20;
    float4 q0 = *(const float4*)(row);
    float4 q1 = *(const float4*)(row+4);
    float4 q2 = *(const float4*)(row+8);
    float4 q3 = *(const float4*)(row+12);
    float4 q4 = *(const float4*)(row+16);
    float u = xib[(size_t)ps*DIC];
    float dt = bdt + q0.x*wdt.x + q0.y*wdt.y + q0.z*wdt.z + q0.w*wdt.w;
    dt = softplusf_(dt);
    float du = dt*u;
    float Bv[NS] = {q1.x,q1.y,q1.z,q1.w,q2.x,q2.y,q2.z,q2.w};
    float Cv[NS] = {q3.x,q3.y,q3.z,q3.w,q4.x,q4.y,q4.z,q4.w};
    float y = 0.f;
    #pragma unroll
    for (int n=0;n<NS;++n){
      h[n] = h[n]*__expf(dt*Arow[n]) + du*Bv[n];
      y += h[n]*Cv[n];
    }
    y += u*Dv;
    atomicAdd(yb + (size_t)ps*DIC, y);
  }
}

// ---------- LN over c per pixel (wave-per-pixel), * ong+onb, * silu(z); in place ----------
__global__ void k_lnz(float* __restrict__ y_t, const float* __restrict__ z_t,
                      const float* __restrict__ ong, const float* __restrict__ onb){
  int gid = blockIdx.x*256 + threadIdx.x;
  int wid = gid >> 6;
  int lane = gid & 63;
  if (wid >= BB*LL) return;
  size_t rb = (size_t)wid * DIC;
  float v0 = y_t[rb + lane];
  float v1 = y_t[rb + 64 + lane];
  float v2 = (lane < 16) ? y_t[rb + 128 + lane] : 0.f;
  float s = v0 + v1 + v2;
  float q = v0*v0 + v1*v1 + v2*v2;
  #pragma unroll
  for (int o=32; o>0; o>>=1){ s += __shfl_xor(s,o,64); q += __shfl_xor(q,o,64); }
  float mu = s*(1.f/DIC);
  float var = q*(1.f/DIC) - mu*mu;
  float rs = rsqrtf(var + 1e-5f);
  float z0 = z_t[rb + lane];
  y_t[rb + lane] = ((v0-mu)*rs*ong[lane] + onb[lane]) * siluf_(z0);
  float z1 = z_t[rb + 64 + lane];
  y_t[rb + 64 + lane] = ((v1-mu)*rs*ong[64+lane] + onb[64+lane]) * siluf_(z1);
  if (lane < 16){
    float z2 = z_t[rb + 128 + lane];
    y_t[rb + 128 + lane] = ((v2-mu)*rs*ong[128+lane] + onb[128+lane]) * siluf_(z2);
  }
}

// ---------- out-proj: LDS-staged y tile (transposed, stride 65), 18 oc per thread ----------
__global__ void k_oproj(const float* __restrict__ y_t, const float* __restrict__ opw,
                        float* __restrict__ xout){
  __shared__ float ly[DIC*65];
  int bid = blockIdx.x;              // BB * 64 tiles
  int tile = bid & 63; int b = bid >> 6;
  int pstart = tile*64;
  const float* src = y_t + ((size_t)b*LL + pstart)*DIC;
  for (int i = threadIdx.x; i < 64*DIC; i += 256){
    int px = i / DIC; int d = i - px*DIC;
    ly[d*65 + px] = src[i];
  }
  __syncthreads();
  int px = threadIdx.x & 63;
  int ocg = __builtin_amdgcn_readfirstlane(threadIdx.x >> 6);  // 0..3 wave-uniform
  float acc[18];
  #pragma unroll
  for (int j=0;j<18;++j) acc[j]=0.f;
  const float* wb = opw + (size_t)ocg*18*DIC;
  #pragma unroll 4
  for (int d=0; d<DIC; ++d){
    float a = ly[d*65 + px];
    #pragma unroll
    for (int j=0;j<18;++j) acc[j] += a * wb[(size_t)j*DIC + d];
  }
  #pragma unroll
  for (int j=0;j<18;++j)
    xout[((size_t)(b*DMC + ocg*18 + j)<<12) + pstart + px] = acc[j];
}

// ---------- groupnorm (12 groups of 6ch) in place ----------
__global__ void k_gn(float* __restrict__ x, const float* __restrict__ g,
                     const float* __restrict__ bta){
  __shared__ float s1[256], s2[256];
  int b = blockIdx.x / GRP; int gr = blockIdx.x % GRP;
  const int CG = DMC/GRP; // 6
  float ls=0.f, lq=0.f;
  for (int i = threadIdx.x; i < CG*LL; i += 256){
    int c = gr*CG + (i>>12); int p = i & 4095;
    float v = x[((size_t)(b*DMC+c)<<12)+p];
    ls += v; lq += v*v;
  }
  s1[threadIdx.x]=ls; s2[threadIdx.x]=lq; __syncthreads();
  for (int s=128; s>0; s>>=1){
    if (threadIdx.x < s){ s1[threadIdx.x]+=s1[threadIdx.x+s]; s2[threadIdx.x]+=s2[threadIdx.x+s]; }
    __syncthreads();
  }
  float mu = s1[0]/(CG*LL);
  float var = s2[0]/(CG*LL) - mu*mu;
  float rs = rsqrtf(var + 1e-5f);
  for (int i = threadIdx.x; i < CG*LL; i += 256){
    int c = gr*CG + (i>>12); int p = i & 4095;
    size_t off = ((size_t)(b*DMC+c)<<12)+p;
    x[off] = (x[off]-mu)*rs*g[c] + bta[c];
  }
}

// ---------- dense 72x72 + bias (+ optional lrelu 0.04), 8 oc/thread ----------
__global__ void k_dense(const float* __restrict__ xin, const float* __restrict__ w,
                        const float* __restrict__ bias, float* __restrict__ xout,
                        float* __restrict__ pad_out, int do_lrelu){
  int bid = blockIdx.x;
  int t = bid & 15; int r = bid >> 4; int eg = r % 9; int b = r / 9;
  int p = t*256 + threadIdx.x;
  float acc[8];
  #pragma unroll
  for (int j=0;j<8;++j) acc[j] = bias[eg*8+j];
  for (int c0=0; c0<DMC; c0+=4){
    float a[4];
    #pragma unroll
    for (int q=0;q<4;++q) a[q] = xin[((size_t)(b*DMC+c0+q)<<12)+p];
    #pragma unroll
    for (int j=0;j<8;++j){
      float4 w0 = *(const float4*)(w + (eg*8+j)*DMC + c0);
      acc[j] += a[0]*w0.x + a[1]*w0.y + a[2]*w0.z + a[3]*w0.w;
    }
  }
  int pb = padidx(p);
  #pragma unroll
  for (int j=0;j<8;++j){
    float a = acc[j];
    if (do_lrelu) a = a >= 0.f ? a : 0.04f*a;
    xout[((size_t)(b*DMC+eg*8+j)<<12)+p] = a;
    if (pad_out) pad_out[(size_t)(b*DMC+eg*8+j)*PP + pb] = a;
  }
}

// ---------- shrink conv 72->6 3x3 + sigmoid, 2 oc/thread, padded input ----------
__global__ void k_shrink(const float* __restrict__ x_pad, const float* __restrict__ w,
                         const float* __restrict__ bias, float* __restrict__ out){
  int bid = blockIdx.x;
  int t = bid & 15; int r = bid >> 4; int o2 = r % 3; int b = r / 3;
  int p = t*256 + threadIdx.x;
  int pb = padidx(p);
  float acc[2] = { bias[o2*2], bias[o2*2+1] };
  const float* ipb = x_pad + (size_t)b*DMC*PP + pb;
  #pragma unroll 2
  for (int ic=0; ic<DMC; ++ic){
    const float* ip = ipb + (size_t)ic*PP;
    float a[9]; LOAD9(ip, a);
    #pragma unroll
    for (int j=0;j<2;++j){
      const float* wp = w + ((o2*2+j)*DMC+ic)*9;
      float s = 0.f;
      #pragma unroll
      for (int q=0;q<9;++q) s += a[q]*wp[q];
      acc[j] += s;
    }
  }
  #pragma unroll
  for (int j=0;j<2;++j)
    out[((size_t)(b*CI+o2*2+j)<<12)+p] = sigmoidf_(acc[j]);
}

extern "C" void kernel_launch(void* const* d_in, const int* in_sizes, int n_in,
                              void* d_out, int out_size, void* d_ws, size_t ws_size,
                              hipStream_t stream){
  const float* image = (const float*)d_in[0];
  const float* cb_w1 = (const float*)d_in[1];
  const float* cb_b1 = (const float*)d_in[2];
  const float* cb_w2 = (const float*)d_in[3];
  const float* cb_b2 = (const float*)d_in[4];
  const float* cb_ws = (const float*)d_in[5];
  const float* cb_bs = (const float*)d_in[6];
  const float* in_w  = (const float*)d_in[7];
  const float* dw_w  = (const float*)d_in[8];
  const float* dw_b  = (const float*)d_in[9];
  const float* xp_w  = (const float*)d_in[10];
  const float* dtp_w = (const float*)d_in[11];
  const float* dtp_b = (const float*)d_in[12];
  const float* A_logs= (const float*)d_in[13];
  const float* Ds    = (const float*)d_in[14];
  const float* ong   = (const float*)d_in[15];
  const float* onb   = (const float*)d_in[16];
  const float* op_w  = (const float*)d_in[17];
  const float* gn_g  = (const float*)d_in[18];
  const float* gn_b  = (const float*)d_in[19];
  const float* l1_w  = (const float*)d_in[20];
  const float* l1_b  = (const float*)d_in[21];
  const float* l2_w  = (const float*)d_in[22];
  const float* l2_b  = (const float*)d_in[23];
  const float* sh_w  = (const float*)d_in[24];
  const float* sh_b  = (const float*)d_in[25];

  const size_t SZ_X  = (size_t)BB*DMC*LL;        // 1,179,648
  const size_t SZ_C  = (size_t)BB*DIC*LL;        // 2,359,296
  const size_t SZ_XD = (size_t)BB*KD*20*LL;      // 1,310,720
  const size_t SZ_IP = (size_t)BB*CI*PP;         // img_pad
  const size_t SZ_TP = (size_t)BB*DMC*PP;        // tmp_pad (= xfin_pad)
  const size_t SZ_ZP = (size_t)BB*DIC*PP;        // xz_pad

  float* ws = (float*)d_ws;
  size_t off = 0;
  float* x     = ws + off; off += SZ_X;
  float* tmp   = ws + off; off += SZ_X;
  float* z_t   = ws + off; off += SZ_C;
  float* xi_t  = ws + off; off += SZ_C;
  float* xdbl  = ws + off; off += SZ_XD;
  float* cumA  = ws + off; off += SZ_C;   // aliased: cumA (p1/p2) then y_t (p3..oproj)
  float* hp    = ws + off; off += SZ_C;
  float* pads  = ws + off;
  float* img_pad = pads;
  float* tmp_pad = img_pad + SZ_IP;       // also xfin_pad for shrink
  float* xz_pad  = tmp_pad + SZ_TP;
  off += SZ_IP + SZ_TP + SZ_ZP;
  if (ws_size < off*sizeof(float)) return;
  float* y_t = cumA;

  dim3 blk(256);

  // zero padded buffers (halos must be 0; interiors are overwritten each call)
  hipMemsetAsync(pads, 0, (SZ_IP+SZ_TP+SZ_ZP)*sizeof(float), stream);

  k_pad_img<<<dim3(BB*CI*16), blk, 0, stream>>>(image, img_pad);
  k_conv1<<<dim3(BB*DMC*16), blk, 0, stream>>>(img_pad, cb_w1, cb_b1, tmp_pad);
  k_conv2<<<dim3(BB*9*16), blk, 0, stream>>>(tmp_pad, image, cb_w2, cb_b2, cb_ws, cb_bs, x);

  for (int i=0; i<NLAYER; ++i){
    const float* in_w_i  = in_w  + (size_t)i*2*DIC*DMC;
    const float* dw_w_i  = dw_w  + (size_t)i*DIC*9;
    const float* dw_b_i  = dw_b  + (size_t)i*DIC;
    const float* xp_w_i  = xp_w  + (size_t)i*KD*20*DIC;
    const float* dtp_w_i = dtp_w + (size_t)i*KD*DIC*RD;
    const float* dtp_b_i = dtp_b + (size_t)i*KD*DIC;
    const float* alog_i  = A_logs+ (size_t)i*KD*DIC*NS;
    const float* Ds_i    = Ds    + (size_t)i*KD*DIC;
    const float* ong_i   = ong   + (size_t)i*DIC;
    const float* onb_i   = onb   + (size_t)i*DIC;
    const float* op_w_i  = op_w  + (size_t)i*DMC*DIC;
    const float* gn_g_i  = gn_g  + (size_t)i*DMC;
    const float* gn_b_i  = gn_b  + (size_t)i*DMC;
    const float* l1_w_i  = l1_w  + (size_t)i*DMC*DMC;
    const float* l1_b_i  = l1_b  + (size_t)i*DMC;
    const float* l2_w_i  = l2_w  + (size_t)i*DMC*DMC;
    const float* l2_b_i  = l2_b  + (size_t)i*DMC;

    k_xz  <<<dim3(BB*36*16), blk, 0, stream>>>(x, in_w_i, xz_pad, z_t);
    k_dw  <<<dim3(BB*DIC*16), blk, 0, stream>>>(xz_pad, dw_w_i, dw_b_i, xi_t);
    k_xdbl<<<dim3(BB*KD*KD*16), blk, 0, stream>>>(xi_t, xp_w_i, xdbl);
    k_p1  <<<dim3(BB*KD*NCH*DIC/256), blk, 0, stream>>>(xi_t, xdbl, dtp_w_i, dtp_b_i, alog_i, cumA, hp);
    k_p2  <<<dim3(BB*KD*NS*DIC/256), blk, 0, stream>>>(cumA, hp);
    hipMemsetAsync(y_t, 0, SZ_C*sizeof(float), stream);
    k_p3  <<<dim3(BB*KD*NCH*DIC/256), blk, 0, stream>>>(xi_t, xdbl, dtp_w_i, dtp_b_i, alog_i, Ds_i, hp, y_t);
    k_lnz <<<dim3(BB*LL/4), blk, 0, stream>>>(y_t, z_t, ong_i, onb_i);
    k_oproj<<<dim3(BB*64), blk, 0, stream>>>(y_t, op_w_i, x);
    k_gn  <<<dim3(BB*GRP), blk, 0, stream>>>(x, gn_g_i, gn_b_i);
    k_dense<<<dim3(BB*9*16), blk, 0, stream>>>(x, l1_w_i, l1_b_i, tmp, (float*)nullptr, 1);
    k_dense<<<dim3(BB*9*16), blk, 0, stream>>>(tmp, l2_w_i, l2_b_i, x,
                                               (i==NLAYER-1) ? tmp_pad : (float*)nullptr, 0);
  }

  k_shrink<<<dim3(BB*3*16), blk, 0, stream>>>(tmp_pad, sh_w, sh_b, (float*)d_out);
}

// Round 6
// 528.179 us; speedup vs baseline: 3.7955x; 1.0913x over previous
//
#include <hip/hip_runtime.h>
#include <math.h>

#define BB 4
#define CI 6
#define LL 4096
#define DMC 72
#define DIC 144
#define KD 4
#define NS 8
#define RD 4
#define NLAYER 2
#define GRP 12
#define NCH 128   // chunks per scan
#define TS 32     // steps per chunk
#define PP 4356   // padded 66x66 plane

__device__ __forceinline__ float sigmoidf_(float x){ return 1.f/(1.f+__expf(-x)); }
__device__ __forceinline__ float siluf_(float x){ return x*sigmoidf_(x); }
// fast softplus: |err| << 2e-3 tolerance
__device__ __forceinline__ float softplusf_(float x){
  return fmaxf(x,0.f) + __logf(1.f + __expf(-fabsf(x)));
}

__device__ __forceinline__ int padidx(int p){ return 66*(p>>6) + (p&63) + 67; }

// spatial position p (row-major h*64+w) for scan index l of direction k
__device__ __forceinline__ int dirmap(int k, int l){
  switch(k & 3){
    case 0: return l;
    case 1: return ((l & 63) << 6) | (l >> 6);
    case 2: return (LL-1) - l;
    default: { int m = (LL-1) - l; return ((m & 63) << 6) | (m >> 6); }
  }
}

#define LOAD9(ip, a) do { \
  a[0]=(ip)[-67]; a[1]=(ip)[-66]; a[2]=(ip)[-65]; \
  a[3]=(ip)[-1];  a[4]=(ip)[0];   a[5]=(ip)[1];   \
  a[6]=(ip)[65];  a[7]=(ip)[66];  a[8]=(ip)[67];  } while(0)

// ---------- zero halos of all padded planes ----------
__global__ void k_halo(float* __restrict__ pads, int nplanes){
  int plane = blockIdx.x;
  if (plane >= nplanes) return;
  int t = threadIdx.x;
  if (t >= 260) return;
  float* pl = pads + (size_t)plane*PP;
  int off;
  if (t < 132){
    int row = (t < 66) ? 0 : 65;
    int col = (t < 66) ? t : t-66;
    off = row*66 + col;
  } else {
    int j = t - 132;
    int col = (j < 64) ? 0 : 65;
    int row = 1 + (j & 63);
    off = row*66 + col;
  }
  pl[off] = 0.f;
}

// ---------- pad copy of the input image ----------
__global__ void k_pad_img(const float* __restrict__ img, float* __restrict__ img_pad){
  int idx = blockIdx.x*256 + threadIdx.x;
  if (idx >= BB*CI*LL) return;
  int p = idx & 4095; int bc = idx >> 12;
  img_pad[(size_t)bc*PP + padidx(p)] = img[idx];
}

// ---------- conv 6->72 3x3 + lrelu(0.01); padded in, padded out ----------
__global__ void k_conv1(const float* __restrict__ img_pad, const float* __restrict__ w,
                        const float* __restrict__ bias, float* __restrict__ tmp_pad){
  int bid = blockIdx.x;
  int t = bid & 15; int r = bid >> 4; int o = r % DMC; int b = r / DMC;
  int p = t*256 + threadIdx.x;
  int pb = padidx(p);
  float acc = bias[o];
  const float* wb = w + o*CI*9;
  #pragma unroll
  for (int ic=0; ic<CI; ++ic){
    const float* ip = img_pad + (size_t)(b*CI+ic)*PP + pb;
    float a[9]; LOAD9(ip, a);
    #pragma unroll
    for (int q=0;q<9;++q) acc += a[q]*wb[ic*9+q];
  }
  tmp_pad[(size_t)(b*DMC+o)*PP + pb] = acc >= 0.f ? acc : 0.01f*acc;
}

// ---------- conv 72->72 3x3 + 1x1 shortcut + lrelu(0.01), 4 oc/thread ----------
__global__ void k_conv2(const float* __restrict__ tmp_pad, const float* __restrict__ img,
                        const float* __restrict__ w2, const float* __restrict__ b2,
                        const float* __restrict__ wsc, const float* __restrict__ bsc,
                        float* __restrict__ xout){
  int bid = blockIdx.x;
  int t = bid & 15; int r = bid >> 4; int og = r % 18; int b = r / 18;
  int p = t*256 + threadIdx.x;
  int pb = padidx(p);
  float acc[4];
  #pragma unroll
  for (int j=0;j<4;++j) acc[j] = b2[og*4+j] + bsc[og*4+j];
  const float* ipb = tmp_pad + (size_t)b*DMC*PP + pb;
  const float* wb  = w2 + (size_t)(og*4)*DMC*9;
  #pragma unroll 2
  for (int ic=0; ic<DMC; ++ic){
    const float* ip = ipb + (size_t)ic*PP;
    float a[9]; LOAD9(ip, a);
    const float* wp = wb + ic*9;
    #pragma unroll
    for (int j=0;j<4;++j){
      float s = 0.f;
      #pragma unroll
      for (int q=0;q<9;++q) s += a[q]*wp[(size_t)j*DMC*9 + q];
      acc[j] += s;
    }
  }
  #pragma unroll
  for (int ic=0; ic<CI; ++ic){
    float v = img[((b*CI+ic)<<12)+p];
    #pragma unroll
    for (int j=0;j<4;++j) acc[j] += v * wsc[(og*4+j)*CI+ic];
  }
  #pragma unroll
  for (int j=0;j<4;++j){
    float a = acc[j];
    xout[((b*DMC+og*4+j)<<12)+p] = a >= 0.f ? a : 0.01f*a;
  }
}

// ---------- xz: first 144 ch -> padded planes (for dw); last 144 (z) -> z_t [b][p][c] ----------
__global__ void k_xz(const float* __restrict__ x, const float* __restrict__ inw,
                     float* __restrict__ xz_pad, float* __restrict__ z_t){
  int bid = blockIdx.x;
  int t = bid & 15; int r = bid >> 4; int eg = r % 36; int b = r / 36;
  int p = t*256 + threadIdx.x;
  float acc[8] = {0.f,0.f,0.f,0.f,0.f,0.f,0.f,0.f};
  for (int c0=0; c0<DMC; c0+=4){
    float a[4];
    #pragma unroll
    for (int q=0;q<4;++q) a[q] = x[((b*DMC+c0+q)<<12)+p];
    #pragma unroll
    for (int j=0;j<8;++j){
      float4 w = *(const float4*)(inw + (eg*8+j)*DMC + c0);
      acc[j] += a[0]*w.x + a[1]*w.y + a[2]*w.z + a[3]*w.w;
    }
  }
  if (eg < 18){
    int pb = padidx(p);
    #pragma unroll
    for (int j=0;j<8;++j) xz_pad[(size_t)(b*DIC+eg*8+j)*PP + pb] = acc[j];
  } else {
    float* zb = z_t + ((size_t)b*LL+p)*DIC + (eg*8-DIC);
    *(float4*)(zb)   = make_float4(acc[0],acc[1],acc[2],acc[3]);
    *(float4*)(zb+4) = make_float4(acc[4],acc[5],acc[6],acc[7]);
  }
}

// ---------- depthwise 3x3 + bias + silu -> xi_t [b][p][c] ----------
__global__ void k_dw(const float* __restrict__ xz_pad, const float* __restrict__ dww,
                     const float* __restrict__ dwb, float* __restrict__ xi_t){
  int bid = blockIdx.x;
  int t = bid & 15; int r = bid >> 4; int c = r % DIC; int b = r / DIC;
  int p = t*256 + threadIdx.x;
  int pb = padidx(p);
  const float* ip = xz_pad + (size_t)(b*DIC+c)*PP + pb;
  const float* wp = dww + c*9;
  float a[9]; LOAD9(ip, a);
  float acc = dwb[c];
  #pragma unroll
  for (int q=0;q<9;++q) acc += a[q]*wp[q];
  xi_t[((size_t)b*LL+p)*DIC + c] = siluf_(acc);
}

// ---------- x_dbl stored as [bk][l(spatial p)][20]; thread=(b,part,k,ptile) ----------
__global__ void k_xdbl(const float* __restrict__ xi_t, const float* __restrict__ xpw,
                       float* __restrict__ xdbl){
  int bid = blockIdx.x;
  int t = bid & 15; int r = bid >> 4;
  int kk = r & 3; r >>= 2; int part = r & 3; int b = r >> 2;
  int p = t*256 + threadIdx.x;
  const float* xib = xi_t + ((size_t)b*LL + p)*DIC;
  const float* wk = xpw + (size_t)(kk*20 + part*5)*DIC;
  float acc[5] = {0.f,0.f,0.f,0.f,0.f};
  for (int d=0; d<DIC; d+=4){
    float4 v = *(const float4*)(xib + d);
    #pragma unroll
    for (int c=0;c<5;++c){
      float4 w = *(const float4*)(wk + (size_t)c*DIC + d);
      acc[c] += v.x*w.x + v.y*w.y + v.z*w.z + v.w*w.w;
    }
  }
  float* dst = xdbl + ((size_t)(b*KD+kk)*LL + p)*20 + part*5;
  #pragma unroll
  for (int c=0;c<5;++c) dst[c] = acc[c];
}

__device__ __forceinline__ void scan_decode(int idx, int& b, int& k, int& ch, int& c){
  c = idx % DIC;
  int r = idx / DIC;
  ch = r % NCH;
  r /= NCH;
  k = r & 3; b = r >> 2;
}

// ---------- P1: per-chunk summaries (cumA, partial state), layout [bk][ch][n][c] ----------
__global__ void k_p1(const float* __restrict__ xi_t, const float* __restrict__ xdbl,
                     const float* __restrict__ dtpw, const float* __restrict__ dtpb,
                     const float* __restrict__ alog,
                     float* __restrict__ cumA, float* __restrict__ hp){
  int idx = blockIdx.x*256 + threadIdx.x;
  if (idx >= BB*KD*NCH*DIC) return;
  int b,k,ch,c; scan_decode(idx,b,k,ch,c);
  float Arow[NS];
  #pragma unroll
  for (int n=0;n<NS;++n) Arow[n] = -__expf(alog[(k*DIC+c)*NS+n]);
  float4 wdt = *(const float4*)(dtpw + (k*DIC+c)*RD);
  float bdt = dtpb[k*DIC+c];
  const float* xd = xdbl + (size_t)(b*KD+k)*LL*20;
  const float* xib = xi_t + (size_t)b*LL*DIC + c;
  float h[NS];
  #pragma unroll
  for (int n=0;n<NS;++n) h[n]=0.f;
  float sumd = 0.f;
  #pragma unroll 2
  for (int t=0; t<TS; ++t){
    int l = ch*TS + t;
    int ps = dirmap(k,l);
    const float* row = xd + (size_t)ps*20;
    float4 q0 = *(const float4*)(row);
    float4 q1 = *(const float4*)(row+4);
    float4 q2 = *(const float4*)(row+8);
    float u = xib[(size_t)ps*DIC];
    float dt = bdt + q0.x*wdt.x + q0.y*wdt.y + q0.z*wdt.z + q0.w*wdt.w;
    dt = softplusf_(dt);
    sumd += dt;
    float du = dt*u;
    float Bv[NS] = {q1.x,q1.y,q1.z,q1.w,q2.x,q2.y,q2.z,q2.w};
    #pragma unroll
    for (int n=0;n<NS;++n)
      h[n] = h[n]*__expf(dt*Arow[n]) + du*Bv[n];
  }
  size_t base = ((size_t)((b*KD+k)*NCH + ch)*NS)*DIC + c;
  #pragma unroll
  for (int n=0;n<NS;++n) hp[base + n*DIC] = h[n];
  #pragma unroll
  for (int n=0;n<NS;++n) cumA[base + n*DIC] = __expf(sumd*Arow[n]);
}

// ---------- P2: prefix over chunk summaries, thread per (bk,n,c); hp becomes h_in ----------
__global__ void k_p2(const float* __restrict__ cumA, float* __restrict__ hp){
  int idx = blockIdx.x*256 + threadIdx.x;
  if (idx >= BB*KD*NS*DIC) return;
  int c = idx % DIC; int n = (idx/DIC) % NS; int bk = idx/(DIC*NS);
  float h = 0.f;
  #pragma unroll 4
  for (int ch=0; ch<NCH; ++ch){
    size_t base = ((size_t)(bk*NCH+ch)*NS + n)*DIC + c;
    float a = cumA[base];
    float pp = hp[base];
    hp[base] = h;
    h = a*h + pp;
  }
}

// ---------- P3: replay chunks, accumulate into y_t [b][p][c] with coalesced atomics ----------
__global__ void k_p3(const float* __restrict__ xi_t, const float* __restrict__ xdbl,
                     const float* __restrict__ dtpw, const float* __restrict__ dtpb,
                     const float* __restrict__ alog, const float* __restrict__ Dsv,
                     const float* __restrict__ hin, float* __restrict__ y_t){
  int idx = blockIdx.x*256 + threadIdx.x;
  if (idx >= BB*KD*NCH*DIC) return;
  int b,k,ch,c; scan_decode(idx,b,k,ch,c);
  float Arow[NS];
  #pragma unroll
  for (int n=0;n<NS;++n) Arow[n] = -__expf(alog[(k*DIC+c)*NS+n]);
  float4 wdt = *(const float4*)(dtpw + (k*DIC+c)*RD);
  float bdt = dtpb[k*DIC+c];
  float Dv = Dsv[k*DIC+c];
  const float* xd = xdbl + (size_t)(b*KD+k)*LL*20;
  const float* xib = xi_t + (size_t)b*LL*DIC + c;
  float* yb = y_t + (size_t)b*LL*DIC + c;
  float h[NS];
  size_t base = ((size_t)((b*KD+k)*NCH + ch)*NS)*DIC + c;
  #pragma unroll
  for (int n=0;n<NS;++n) h[n] = hin[base + n*DIC];
  #pragma unroll 2
  for (int t=0; t<TS; ++t){
    int l = ch*TS + t;
    int ps = dirmap(k,l);
    const float* row = xd + (size_t)ps*20;
    float4 q0 = *(const float4*)(row);
    float4 q1 = *(const float4*)(row+4);
    float4 q2 = *(const float4*)(row+8);
    float4 q3 = *(const float4*)(row+12);
    float4 q4 = *(const float4*)(row+16);
    float u = xib[(size_t)ps*DIC];
    float dt = bdt + q0.x*wdt.x + q0.y*wdt.y + q0.z*wdt.z + q0.w*wdt.w;
    dt = softplusf_(dt);
    float du = dt*u;
    float Bv[NS] = {q1.x,q1.y,q1.z,q1.w,q2.x,q2.y,q2.z,q2.w};
    float Cv[NS] = {q3.x,q3.y,q3.z,q3.w,q4.x,q4.y,q4.z,q4.w};
    float y = 0.f;
    #pragma unroll
    for (int n=0;n<NS;++n){
      h[n] = h[n]*__expf(dt*Arow[n]) + du*Bv[n];
      y += h[n]*Cv[n];
    }
    y += u*Dv;
    atomicAdd(yb + (size_t)ps*DIC, y);
  }
}

// ---------- out-proj fused with LN(y)*ong+onb and *silu(z) ----------
__global__ void k_oproj(const float* __restrict__ y_t, const float* __restrict__ z_t,
                        const float* __restrict__ ong, const float* __restrict__ onb,
                        const float* __restrict__ opw, float* __restrict__ xout){
  __shared__ float ly[DIC*65];
  __shared__ float red1[4][64], red2[4][64];
  __shared__ float lmu[64], lrs[64];
  int bid = blockIdx.x;              // BB * 64 tiles
  int tile = bid & 63; int b = bid >> 6;
  int pstart = tile*64;
  const float* src = y_t + ((size_t)b*LL + pstart)*DIC;
  for (int i = threadIdx.x; i < 64*DIC; i += 256){
    int px = i / DIC; int d = i - px*DIC;
    ly[d*65 + px] = src[i];
  }
  __syncthreads();
  int px = threadIdx.x & 63;
  int grp = threadIdx.x >> 6;
  {
    float s=0.f, q=0.f;
    for (int d=grp*36; d<grp*36+36; ++d){
      float v = ly[d*65+px]; s += v; q += v*v;
    }
    red1[grp][px]=s; red2[grp][px]=q;
  }
  __syncthreads();
  if (grp == 0){
    float st = red1[0][px]+red1[1][px]+red1[2][px]+red1[3][px];
    float qt = red2[0][px]+red2[1][px]+red2[2][px]+red2[3][px];
    float mu = st*(1.f/DIC);
    float var = qt*(1.f/DIC) - mu*mu;
    lmu[px] = mu;
    lrs[px] = rsqrtf(var + 1e-5f);
  }
  __syncthreads();
  const float* zsrc = z_t + ((size_t)b*LL + pstart)*DIC;
  for (int i = threadIdx.x; i < 64*DIC; i += 256){
    int ppx = i / DIC; int d = i - ppx*DIC;
    float zv = zsrc[i];
    float v = ly[d*65+ppx];
    ly[d*65+ppx] = ((v - lmu[ppx])*lrs[ppx]*ong[d] + onb[d]) * siluf_(zv);
  }
  __syncthreads();
  int ocg = __builtin_amdgcn_readfirstlane(grp);  // 0..3 wave-uniform
  float acc[18];
  #pragma unroll
  for (int j=0;j<18;++j) acc[j]=0.f;
  const float* wb = opw + (size_t)ocg*18*DIC;
  #pragma unroll 4
  for (int d=0; d<DIC; ++d){
    float a = ly[d*65 + px];
    #pragma unroll
    for (int j=0;j<18;++j) acc[j] += a * wb[(size_t)j*DIC + d];
  }
  #pragma unroll
  for (int j=0;j<18;++j)
    xout[((size_t)(b*DMC + ocg*18 + j)<<12) + pstart + px] = acc[j];
}

// ---------- groupnorm (12 groups of 6ch) in place ----------
__global__ void k_gn(float* __restrict__ x, const float* __restrict__ g,
                     const float* __restrict__ bta){
  __shared__ float s1[256], s2[256];
  int b = blockIdx.x / GRP; int gr = blockIdx.x % GRP;
  const int CG = DMC/GRP; // 6
  float ls=0.f, lq=0.f;
  for (int i = threadIdx.x; i < CG*LL; i += 256){
    int c = gr*CG + (i>>12); int p = i & 4095;
    float v = x[((size_t)(b*DMC+c)<<12)+p];
    ls += v; lq += v*v;
  }
  s1[threadIdx.x]=ls; s2[threadIdx.x]=lq; __syncthreads();
  for (int s=128; s>0; s>>=1){
    if (threadIdx.x < s){ s1[threadIdx.x]+=s1[threadIdx.x+s]; s2[threadIdx.x]+=s2[threadIdx.x+s]; }
    __syncthreads();
  }
  float mu = s1[0]/(CG*LL);
  float var = s2[0]/(CG*LL) - mu*mu;
  float rs = rsqrtf(var + 1e-5f);
  for (int i = threadIdx.x; i < CG*LL; i += 256){
    int c = gr*CG + (i>>12); int p = i & 4095;
    size_t off = ((size_t)(b*DMC+c)<<12)+p;
    x[off] = (x[off]-mu)*rs*g[c] + bta[c];
  }
}

// ---------- dense 72x72 + bias (+ optional lrelu 0.04), 4 oc/thread ----------
__global__ void k_dense(const float* __restrict__ xin, const float* __restrict__ w,
                        const float* __restrict__ bias, float* __restrict__ xout,
                        float* __restrict__ pad_out, int do_lrelu){
  int bid = blockIdx.x;
  int t = bid & 15; int r = bid >> 4; int eg = r % 18; int b = r / 18;
  int p = t*256 + threadIdx.x;
  float acc[4];
  #pragma unroll
  for (int j=0;j<4;++j) acc[j] = bias[eg*4+j];
  for (int c0=0; c0<DMC; c0+=4){
    float a[4];
    #pragma unroll
    for (int q=0;q<4;++q) a[q] = xin[((size_t)(b*DMC+c0+q)<<12)+p];
    #pragma unroll
    for (int j=0;j<4;++j){
      float4 w0 = *(const float4*)(w + (eg*4+j)*DMC + c0);
      acc[j] += a[0]*w0.x + a[1]*w0.y + a[2]*w0.z + a[3]*w0.w;
    }
  }
  int pb = padidx(p);
  #pragma unroll
  for (int j=0;j<4;++j){
    float a = acc[j];
    if (do_lrelu) a = a >= 0.f ? a : 0.04f*a;
    xout[((size_t)(b*DMC+eg*4+j)<<12)+p] = a;
    if (pad_out) pad_out[(size_t)(b*DMC+eg*4+j)*PP + pb] = a;
  }
}

// ---------- shrink conv pass A: ic-split partials, 6 oc, atomic accumulate ----------
__global__ void k_shrinkA(const float* __restrict__ x_pad, const float* __restrict__ w,
                          float* __restrict__ pacc){
  int bid = blockIdx.x;   // b(4) * icg(8) * tile(16)
  int t = bid & 15; int r = bid >> 4; int icg = r & 7; int b = r >> 3;
  int p = t*256 + threadIdx.x;
  int pb = padidx(p);
  float acc[6] = {0.f,0.f,0.f,0.f,0.f,0.f};
  const float* ipb = x_pad + (size_t)b*DMC*PP + pb;
  #pragma unroll
  for (int ii=0; ii<9; ++ii){
    int ic = icg*9 + ii;
    const float* ip = ipb + (size_t)ic*PP;
    float a[9]; LOAD9(ip, a);
    #pragma unroll
    for (int o=0;o<6;++o){
      const float* wp = w + (o*DMC+ic)*9;
      float s = 0.f;
      #pragma unroll
      for (int q=0;q<9;++q) s += a[q]*wp[q];
      acc[o] += s;
    }
  }
  #pragma unroll
  for (int o=0;o<6;++o)
    atomicAdd(pacc + ((size_t)(b*CI+o)<<12)+p, acc[o]);
}

// ---------- shrink pass B: bias + sigmoid ----------
__global__ void k_sig(const float* __restrict__ pacc, const float* __restrict__ bias,
                      float* __restrict__ out){
  int idx = blockIdx.x*256 + threadIdx.x;
  if (idx >= BB*CI*LL) return;
  int o = (idx>>12) % CI;
  out[idx] = sigmoidf_(pacc[idx] + bias[o]);
}

extern "C" void kernel_launch(void* const* d_in, const int* in_sizes, int n_in,
                              void* d_out, int out_size, void* d_ws, size_t ws_size,
                              hipStream_t stream){
  const float* image = (const float*)d_in[0];
  const float* cb_w1 = (const float*)d_in[1];
  const float* cb_b1 = (const float*)d_in[2];
  const float* cb_w2 = (const float*)d_in[3];
  const float* cb_b2 = (const float*)d_in[4];
  const float* cb_ws = (const float*)d_in[5];
  const float* cb_bs = (const float*)d_in[6];
  const float* in_w  = (const float*)d_in[7];
  const float* dw_w  = (const float*)d_in[8];
  const float* dw_b  = (const float*)d_in[9];
  const float* xp_w  = (const float*)d_in[10];
  const float* dtp_w = (const float*)d_in[11];
  const float* dtp_b = (const float*)d_in[12];
  const float* A_logs= (const float*)d_in[13];
  const float* Ds    = (const float*)d_in[14];
  const float* ong   = (const float*)d_in[15];
  const float* onb   = (const float*)d_in[16];
  const float* op_w  = (const float*)d_in[17];
  const float* gn_g  = (const float*)d_in[18];
  const float* gn_b  = (const float*)d_in[19];
  const float* l1_w  = (const float*)d_in[20];
  const float* l1_b  = (const float*)d_in[21];
  const float* l2_w  = (const float*)d_in[22];
  const float* l2_b  = (const float*)d_in[23];
  const float* sh_w  = (const float*)d_in[24];
  const float* sh_b  = (const float*)d_in[25];

  const size_t SZ_X  = (size_t)BB*DMC*LL;        // 1,179,648
  const size_t SZ_C  = (size_t)BB*DIC*LL;        // 2,359,296
  const size_t SZ_XD = (size_t)BB*KD*20*LL;      // 1,310,720
  const size_t SZ_IP = (size_t)BB*CI*PP;         // img_pad
  const size_t SZ_TP = (size_t)BB*DMC*PP;        // tmp_pad (= xfin_pad)
  const size_t SZ_ZP = (size_t)BB*DIC*PP;        // xz_pad

  float* ws = (float*)d_ws;
  size_t off = 0;
  float* x     = ws + off; off += SZ_X;
  float* tmp   = ws + off; off += SZ_X;   // dense l1 out; later shrink pacc
  float* z_t   = ws + off; off += SZ_C;
  float* xi_t  = ws + off; off += SZ_C;
  float* xdbl  = ws + off; off += SZ_XD;
  float* cumA  = ws + off; off += SZ_C;   // aliased: cumA (p1/p2) then y_t (p3..oproj)
  float* hp    = ws + off; off += SZ_C;
  float* pads  = ws + off;
  float* img_pad = pads;
  float* tmp_pad = img_pad + SZ_IP;       // also xfin_pad for shrink
  float* xz_pad  = tmp_pad + SZ_TP;
  off += SZ_IP + SZ_TP + SZ_ZP;
  if (ws_size < off*sizeof(float)) return;
  float* y_t = cumA;

  dim3 blk(256);
  const int NPLANES = BB*CI + BB*DMC + BB*DIC;   // 888 padded planes

  k_halo<<<dim3(NPLANES), blk, 0, stream>>>(pads, NPLANES);
  k_pad_img<<<dim3(BB*CI*16), blk, 0, stream>>>(image, img_pad);
  k_conv1<<<dim3(BB*DMC*16), blk, 0, stream>>>(img_pad, cb_w1, cb_b1, tmp_pad);
  k_conv2<<<dim3(BB*18*16), blk, 0, stream>>>(tmp_pad, image, cb_w2, cb_b2, cb_ws, cb_bs, x);

  for (int i=0; i<NLAYER; ++i){
    const float* in_w_i  = in_w  + (size_t)i*2*DIC*DMC;
    const float* dw_w_i  = dw_w  + (size_t)i*DIC*9;
    const float* dw_b_i  = dw_b  + (size_t)i*DIC;
    const float* xp_w_i  = xp_w  + (size_t)i*KD*20*DIC;
    const float* dtp_w_i = dtp_w + (size_t)i*KD*DIC*RD;
    const float* dtp_b_i = dtp_b + (size_t)i*KD*DIC;
    const float* alog_i  = A_logs+ (size_t)i*KD*DIC*NS;
    const float* Ds_i    = Ds    + (size_t)i*KD*DIC;
    const float* ong_i   = ong   + (size_t)i*DIC;
    const float* onb_i   = onb   + (size_t)i*DIC;
    const float* op_w_i  = op_w  + (size_t)i*DMC*DIC;
    const float* gn_g_i  = gn_g  + (size_t)i*DMC;
    const float* gn_b_i  = gn_b  + (size_t)i*DMC;
    const float* l1_w_i  = l1_w  + (size_t)i*DMC*DMC;
    const float* l1_b_i  = l1_b  + (size_t)i*DMC;
    const float* l2_w_i  = l2_w  + (size_t)i*DMC*DMC;
    const float* l2_b_i  = l2_b  + (size_t)i*DMC;

    k_xz  <<<dim3(BB*36*16), blk, 0, stream>>>(x, in_w_i, xz_pad, z_t);
    k_dw  <<<dim3(BB*DIC*16), blk, 0, stream>>>(xz_pad, dw_w_i, dw_b_i, xi_t);
    k_xdbl<<<dim3(BB*KD*KD*16), blk, 0, stream>>>(xi_t, xp_w_i, xdbl);
    k_p1  <<<dim3(BB*KD*NCH*DIC/256), blk, 0, stream>>>(xi_t, xdbl, dtp_w_i, dtp_b_i, alog_i, cumA, hp);
    k_p2  <<<dim3(BB*KD*NS*DIC/256), blk, 0, stream>>>(cumA, hp);
    hipMemsetAsync(y_t, 0, SZ_C*sizeof(float), stream);
    k_p3  <<<dim3(BB*KD*NCH*DIC/256), blk, 0, stream>>>(xi_t, xdbl, dtp_w_i, dtp_b_i, alog_i, Ds_i, hp, y_t);
    k_oproj<<<dim3(BB*64), blk, 0, stream>>>(y_t, z_t, ong_i, onb_i, op_w_i, x);
    k_gn  <<<dim3(BB*GRP), blk, 0, stream>>>(x, gn_g_i, gn_b_i);
    k_dense<<<dim3(BB*18*16), blk, 0, stream>>>(x, l1_w_i, l1_b_i, tmp, (float*)nullptr, 1);
    k_dense<<<dim3(BB*18*16), blk, 0, stream>>>(tmp, l2_w_i, l2_b_i, x,
                                                (i==NLAYER-1) ? tmp_pad : (float*)nullptr, 0);
  }

  // shrink: split-ic partials into tmp (reused as pacc), then bias+sigmoid
  hipMemsetAsync(tmp, 0, (size_t)BB*CI*LL*sizeof(float), stream);
  k_shrinkA<<<dim3(BB*8*16), blk, 0, stream>>>(tmp_pad, sh_w, tmp);
  k_sig<<<dim3((BB*CI*LL+255)/256), blk, 0, stream>>>(tmp, sh_b, (float*)d_out);
}